// Round 3
// baseline (642.321 us; speedup 1.0000x reference)
//
#include <hip/hip_runtime.h>

#define N_K 20000
#define N_E 50000
#define N_U 100000
#define E_UND 200000
#define E_EK 400000
#define E_EU 600000
#define E_TOT 2200000
#define N_TOT 240000
// padded (64-aligned) agg-row segment bases: GAT1 kn | GAT2 kn | GAT3 exer | GAT4 stu | GAT5 exer
#define PB1 0
#define PB2 20032
#define PB3 40064
#define PB4 90112
#define PB5 190144
#define PTOT 240192
// gout compact bases (seg 3 = student goes straight to d_out)
#define GB5 90112
#define GTOT 140160

typedef unsigned short u16;
typedef unsigned int u32;
typedef __bf16 bf16x8 __attribute__((ext_vector_type(8)));
typedef float f32x4 __attribute__((ext_vector_type(4)));

__device__ __forceinline__ float bf2f(u16 v){
    union { u32 u; float f; } x; x.u = ((u32)v) << 16; return x.f;
}
__device__ __forceinline__ u16 f2bf(float f){
    union { float f; u32 u; } x; x.f = f;
    u32 r = x.u + 0x7FFFu + ((x.u >> 16) & 1u);
    return (u16)(r >> 16);
}

// ---------------------------------------------------------------- prep: wl/wr
// wl_g = W_g @ a_g[:128] at vecs+g*128 ; wr_g = W_g @ a_g[128:] at vecs+(5+g)*128
__global__ void prep_vecs(const float* W0, const float* W1, const float* W2, const float* W3, const float* W4,
                          const float* a0, const float* a1, const float* a2, const float* a3, const float* a4,
                          float* __restrict__ vecs)
{
    int b = blockIdx.x;          // 0..9
    int g = b % 5, which = b / 5;
    const float* W = g==0?W0:g==1?W1:g==2?W2:g==3?W3:W4;
    const float* a = g==0?a0:g==1?a1:g==2?a2:g==3?a3:a4;
    const float* av = a + which*128;
    int k = threadIdx.x;         // 0..127
    float sum = 0.f;
    for (int c = 0; c < 128; ++c)
        sum += W[k*128 + c] * av[c];
    vecs[(which*5 + g)*128 + k] = sum;
}

// -------------------------------------------- W -> MFMA-B-fragment order (bf16)
// B frag of mfma_f32_16x16x32_bf16: lane l holds B[k][n], n=ct*16+(l&15),
// k = ks*32 + (l>>4)*8 + j. Linear frag index t = ct*4+ks.
__global__ void fragify(const float* W0, const float* W1, const float* W2, const float* W3, const float* W4,
                        u16* __restrict__ Wf)
{
    int g = blockIdx.x;
    const float* W = g==0?W0:g==1?W1:g==2?W2:g==3?W3:W4;
    u16* out = Wf + g*16384;
    for (int i = threadIdx.x; i < 2048; i += blockDim.x){
        int lane = i & 63, t = i >> 6, ks = t & 3, ct = t >> 2;
        int kbase = ks*32 + (lane>>4)*8;
        int c = ct*16 + (lane&15);
        #pragma unroll
        for (int j = 0; j < 8; ++j)
            out[i*8 + j] = f2bf(W[(kbase+j)*128 + c]);
    }
}

// ------------------------------------------------- fused row-dot kernels (f32 in)
__global__ __launch_bounds__(256) void dot4(const float* __restrict__ h,
    const float* __restrict__ v0, const float* __restrict__ v1,
    const float* __restrict__ v2, const float* __restrict__ v3,
    float* __restrict__ o0, float* __restrict__ o1,
    float* __restrict__ o2, float* __restrict__ o3, int nrows)
{
    int w = (int)((blockIdx.x*(u32)blockDim.x + threadIdx.x) >> 6);
    int lane = threadIdx.x & 63;
    if (w >= nrows) return;
    float2 hv = *(const float2*)(h + (size_t)w*128 + lane*2);
    int c = lane*2;
    float d0 = hv.x*v0[c] + hv.y*v0[c+1];
    float d1 = hv.x*v1[c] + hv.y*v1[c+1];
    float d2 = hv.x*v2[c] + hv.y*v2[c+1];
    float d3 = hv.x*v3[c] + hv.y*v3[c+1];
    #pragma unroll
    for (int o = 32; o; o >>= 1){
        d0 += __shfl_xor(d0, o); d1 += __shfl_xor(d1, o);
        d2 += __shfl_xor(d2, o); d3 += __shfl_xor(d3, o);
    }
    if (lane == 0){ o0[w]=d0; o1[w]=d1; o2[w]=d2; o3[w]=d3; }
}

__global__ __launch_bounds__(256) void dot2(const float* __restrict__ h,
    const float* __restrict__ v0, const float* __restrict__ v1,
    float* __restrict__ o0, float* __restrict__ o1, int nrows)
{
    int w = (int)((blockIdx.x*(u32)blockDim.x + threadIdx.x) >> 6);
    int lane = threadIdx.x & 63;
    if (w >= nrows) return;
    float2 hv = *(const float2*)(h + (size_t)w*128 + lane*2);
    int c = lane*2;
    float d0 = hv.x*v0[c] + hv.y*v0[c+1];
    float d1 = hv.x*v1[c] + hv.y*v1[c+1];
    #pragma unroll
    for (int o = 32; o; o >>= 1){
        d0 += __shfl_xor(d0, o); d1 += __shfl_xor(d1, o);
    }
    if (lane == 0){ o0[w]=d0; o1[w]=d1; }
}

// ------------------------------------------------- f32 -> bf16 embedding conversion
__global__ void convbf(const float* __restrict__ in, u16* __restrict__ outp, int n4){
    int i = blockIdx.x*256 + threadIdx.x;
    if (i >= n4) return;
    float4 v = ((const float4*)in)[i];
    u32 lo = (u32)f2bf(v.x) | ((u32)f2bf(v.y) << 16);
    u32 hi = (u32)f2bf(v.z) | ((u32)f2bf(v.w) << 16);
    ((uint2*)outp)[i] = make_uint2(lo, hi);
}

// ------------------------------------------------- CSR build (all 5 graphs fused)
__global__ void count_all(const int* __restrict__ ud,
                          const int* __restrict__ es, const int* __restrict__ ed,
                          const int* __restrict__ vs, const int* __restrict__ vd,
                          int* __restrict__ cnt)
{
    int e = blockIdx.x*256 + threadIdx.x;
    if (e >= E_TOT) return;
    int dstv, nb;
    if (e < 200000){ dstv = ud[e]; nb = 0; }
    else if (e < 600000){ dstv = ed[e-200000]; nb = 20000; }
    else if (e < 1000000){ dstv = es[e-600000]; nb = 40000; }
    else if (e < 1600000){ dstv = vd[e-1000000]; nb = 90000; }
    else { dstv = vs[e-1600000]; nb = 190000; }
    atomicAdd(&cnt[nb + dstv], 1);
}

__global__ void fill_all(const int* __restrict__ us, const int* __restrict__ ud,
                         const int* __restrict__ es, const int* __restrict__ ed,
                         const int* __restrict__ vs, const int* __restrict__ vd,
                         int* __restrict__ cur, int* __restrict__ sorted)
{
    int e = blockIdx.x*256 + threadIdx.x;
    if (e >= E_TOT) return;
    int srcv, dstv, nb;
    if (e < 200000){ srcv = us[e]; dstv = ud[e]; nb = 0; }
    else if (e < 600000){ int i=e-200000; srcv = es[i]; dstv = ed[i]; nb = 20000; }
    else if (e < 1000000){ int i=e-600000; srcv = ed[i]; dstv = es[i]; nb = 40000; }
    else if (e < 1600000){ int i=e-1000000; srcv = vs[i]; dstv = vd[i]; nb = 90000; }
    else { int i=e-1600000; srcv = vd[i]; dstv = vs[i]; nb = 190000; }
    int pos = atomicAdd(&cur[nb + dstv], 1);
    sorted[pos] = srcv;
}

// block-level exclusive scan (Hillis-Steele in LDS)
__global__ void scan1(const int* __restrict__ cnt, int* __restrict__ off, int* __restrict__ bsum, int n){
    __shared__ int sm[256];
    int t = threadIdx.x;
    int i = blockIdx.x*256 + t;
    int v = (i < n) ? cnt[i] : 0;
    sm[t] = v; __syncthreads();
    #pragma unroll
    for (int d = 1; d < 256; d <<= 1){
        int x = (t >= d) ? sm[t-d] : 0;
        __syncthreads();
        sm[t] += x;
        __syncthreads();
    }
    if (i < n) off[i] = sm[t] - v;
    if (t == 255) bsum[blockIdx.x] = sm[255];
}

__global__ void scan2(int* __restrict__ bsum, int nb){
    __shared__ int sm[1024];
    int t = threadIdx.x;
    int v = (t < nb) ? bsum[t] : 0;
    sm[t] = v; __syncthreads();
    #pragma unroll
    for (int d = 1; d < 1024; d <<= 1){
        int x = (t >= d) ? sm[t-d] : 0;
        __syncthreads();
        sm[t] += x;
        __syncthreads();
    }
    if (t < nb) bsum[t] = sm[t] - v;
}

__global__ void scan3(int* __restrict__ off, int* __restrict__ cur, const int* __restrict__ bsum, int n){
    int i = blockIdx.x*256 + threadIdx.x;
    if (i < n){
        int v = off[i] + bsum[blockIdx.x];
        off[i] = v;
        cur[i] = v;
    }
}

// ------------------------------------------------- fused GAT aggregation (wave per dst node)
// agg[d] = (sum_e ev*h[src_e]) / (sum_e ev), ev = exp(leaky(el[src_e]+er[d])).
// max-shift skipped: el+er ~ N(0,2), max |x| ~ 8 over 2.2M edges -> exp safe; softmax shift-invariant.
template<int BF>
__global__ __launch_bounds__(256) void aggregate_all(
    const int* __restrict__ cnt, const int* __restrict__ off, const int* __restrict__ sorted,
    const float* __restrict__ el1, const float* __restrict__ el2, const float* __restrict__ el3,
    const float* __restrict__ el4, const float* __restrict__ el5,
    const float* __restrict__ er1, const float* __restrict__ er2, const float* __restrict__ er3,
    const float* __restrict__ er4, const float* __restrict__ er5,
    const void* __restrict__ hk, const void* __restrict__ he, const void* __restrict__ hs,
    u16* __restrict__ agg)
{
    int row = (int)((blockIdx.x*(u32)blockDim.x + threadIdx.x) >> 6);
    int lane = threadIdx.x & 63;
    if (row >= PTOT) return;
    int local, nb, sn;
    const float *el, *er;
    const void* h;
    if (row < PB2){ local=row;      nb=0;      sn=N_K; el=el1; er=er1; h=hk; }
    else if (row < PB3){ local=row-PB2; nb=20000;  sn=N_K; el=el2; er=er2; h=he; }
    else if (row < PB4){ local=row-PB3; nb=40000;  sn=N_E; el=el3; er=er3; h=hk; }
    else if (row < PB5){ local=row-PB4; nb=90000;  sn=N_U; el=el4; er=er4; h=he; }
    else {              local=row-PB5; nb=190000; sn=N_E; el=el5; er=er5; h=hs; }
    if (local >= sn) return;   // 64-pad tail
    int ci = nb + local;
    int deg = cnt[ci], start = off[ci];
    float erd = er[local];
    float a0 = 0.f, a1 = 0.f, ssum = 0.f;
    for (int i = 0; i < deg; ++i){
        int si = sorted[start + i];
        float x = el[si] + erd;
        x = x >= 0.f ? x : 0.01f*x;
        float ev = __expf(x);
        float x0, x1;
        if (BF){
            u32 hv = *((const u32*)h + (size_t)si*64 + lane);
            x0 = bf2f((u16)hv); x1 = bf2f((u16)(hv>>16));
        } else {
            float2 hv = *((const float2*)h + (size_t)si*64 + lane);
            x0 = hv.x; x1 = hv.y;
        }
        a0 = fmaf(ev, x0, a0);
        a1 = fmaf(ev, x1, a1);
        ssum += ev;
    }
    float inv = (ssum > 0.f) ? 1.f/ssum : 0.f;   // deg==0 -> zero row (matches reference)
    *(u32*)(agg + (size_t)row*128 + lane*2) = (u32)f2bf(a0*inv) | ((u32)f2bf(a1*inv) << 16);
}

// ------------------------------------------------- fused agg(bf16) @ W_g
// segs 0,1,2,4 -> bf16 gout (compact padded layout); seg 3 (student) -> f32 d_out + resid
__global__ __launch_bounds__(256) void gemm_all(const u16* __restrict__ agg, const u16* __restrict__ Wf,
    u16* __restrict__ gout, float* __restrict__ outstu, const float* __restrict__ resid)
{
    int wave = threadIdx.x >> 6, lane = threadIdx.x & 63;
    int rowbase = blockIdx.x*64 + wave*16;
    int segbase, sn, g, gb;
    if (rowbase < PB2){ segbase=PB1; sn=N_K; g=0; gb=PB1; }
    else if (rowbase < PB3){ segbase=PB2; sn=N_K; g=1; gb=PB2; }
    else if (rowbase < PB4){ segbase=PB3; sn=N_E; g=2; gb=PB3; }
    else if (rowbase < PB5){ segbase=PB4; sn=N_U; g=3; gb=-1; }
    else { segbase=PB5; sn=N_E; g=4; gb=GB5; }
    int local0 = rowbase - segbase;
    if (local0 >= sn) return;   // pad chunk (sn % 16 == 0, so surviving waves are fully real)
    const u16* ap = agg + (size_t)(rowbase + (lane & 15))*128 + ((lane>>4)*8);
    bf16x8 afrag[4];
    #pragma unroll
    for (int ks = 0; ks < 4; ++ks)
        afrag[ks] = *(const bf16x8*)(ap + ks*32);
    const u16* wfp = Wf + g*16384;
    f32x4 acc[8];
    #pragma unroll
    for (int ct = 0; ct < 8; ++ct) acc[ct] = (f32x4){0.f,0.f,0.f,0.f};
    #pragma unroll
    for (int ks = 0; ks < 4; ++ks){
        #pragma unroll
        for (int ct = 0; ct < 8; ++ct){
            bf16x8 b = *(const bf16x8*)(wfp + ((size_t)((ct*4+ks)*64 + lane))*8);
            acc[ct] = __builtin_amdgcn_mfma_f32_16x16x32_bf16(afrag[ks], b, acc[ct], 0, 0, 0);
        }
    }
    int rlo = (lane>>4)*4;
    int colb = lane & 15;
    if (g == 3){
        #pragma unroll
        for (int ct = 0; ct < 8; ++ct){
            #pragma unroll
            for (int j = 0; j < 4; ++j){
                size_t idx = (size_t)(local0 + rlo + j)*128 + ct*16 + colb;
                outstu[idx] = acc[ct][j] + resid[idx];
            }
        }
    } else {
        #pragma unroll
        for (int ct = 0; ct < 8; ++ct){
            #pragma unroll
            for (int j = 0; j < 4; ++j){
                size_t idx = (size_t)(gb + local0 + rlo + j)*128 + ct*16 + colb;
                gout[idx] = f2bf(acc[ct][j]);
            }
        }
    }
}

// ------------------------------------------------- gating epilogue (kn & exer), f32 out
__global__ __launch_bounds__(256) void fuse_epi(const float* __restrict__ A,
    const u16* __restrict__ C, const u16* __restrict__ D,
    const float* __restrict__ w2, const float* __restrict__ b2,
    const float* __restrict__ w3, const float* __restrict__ b3,
    float* __restrict__ outp, int n)
{
    int w = (int)((blockIdx.x*(u32)blockDim.x + threadIdx.x) >> 6);
    int lane = threadIdx.x & 63;
    if (w >= n) return;
    int c = lane*2;
    float2 av = *(const float2*)(A + (size_t)w*128 + c);
    u32 cv = *(const u32*)(C + (size_t)w*128 + c);
    u32 dv = *(const u32*)(D + (size_t)w*128 + c);
    float c0 = bf2f((u16)cv), c1 = bf2f((u16)(cv>>16));
    float d0 = bf2f((u16)dv), d1 = bf2f((u16)(dv>>16));
    float s2 = av.x*w2[c] + av.y*w2[c+1] + c0*w2[128+c] + c1*w2[128+c+1];
    float s3 = av.x*w3[c] + av.y*w3[c+1] + d0*w3[128+c] + d1*w3[128+c+1];
    #pragma unroll
    for (int o = 32; o; o >>= 1){ s2 += __shfl_xor(s2, o); s3 += __shfl_xor(s3, o); }
    s2 += b2[0]; s3 += b3[0];
    float m = fmaxf(s2, s3);
    float e2 = __expf(s2 - m), e3 = __expf(s3 - m);
    float inv = 1.f/(e2 + e3);
    float p2 = e2*inv, p3 = e3*inv;
    float2 r;
    r.x = av.x + p2*c0 + p3*d0;
    r.y = av.y + p2*c1 + p3*d1;
    *(float2*)(outp + (size_t)w*128 + c) = r;
}

extern "C" void kernel_launch(void* const* d_in, const int* in_sizes, int n_in,
                              void* d_out, int out_size, void* d_ws, size_t ws_size,
                              hipStream_t stream)
{
    (void)in_sizes; (void)n_in; (void)out_size;
    const float* kn   = (const float*)d_in[0];
    const float* exer = (const float*)d_in[1];
    const float* stu  = (const float*)d_in[2];
    const int* und_src = (const int*)d_in[3];
    const int* und_dst = (const int*)d_in[4];
    const int* ek_src  = (const int*)d_in[5];
    const int* ek_dst  = (const int*)d_in[6];
    const int* eu_src  = (const int*)d_in[7];
    const int* eu_dst  = (const int*)d_in[8];
    const float* W_und = (const float*)d_in[9];  const float* a_und = (const float*)d_in[10];
    const float* W_ek  = (const float*)d_in[11]; const float* a_ek  = (const float*)d_in[12];
    const float* W_ke  = (const float*)d_in[13]; const float* a_ke  = (const float*)d_in[14];
    const float* W_eu  = (const float*)d_in[15]; const float* a_eu  = (const float*)d_in[16];
    const float* W_ue  = (const float*)d_in[17]; const float* a_ue  = (const float*)d_in[18];
    const float* kfc2w = (const float*)d_in[19]; const float* kfc2b = (const float*)d_in[20];
    const float* kfc3w = (const float*)d_in[21]; const float* kfc3b = (const float*)d_in[22];
    const float* efc1w = (const float*)d_in[23]; const float* efc1b = (const float*)d_in[24];
    const float* efc2w = (const float*)d_in[25]; const float* efc2b = (const float*)d_in[26];

    char* base = (char*)d_ws;
    size_t off_b = 0;
    auto alloc = [&](size_t bytes)->char*{
        char* p = base + off_b;
        off_b += (bytes + 255) & ~(size_t)255;
        return p;
    };
    float* vecs = (float*)alloc(1280*4);
    u16*   Wf   = (u16*)  alloc(5*16384*2);
    float* el1 = (float*)alloc(N_K*4);  float* er1 = (float*)alloc(N_K*4);
    float* er2 = (float*)alloc(N_K*4);  float* el3 = (float*)alloc(N_K*4);
    float* el2 = (float*)alloc(N_E*4);  float* er3 = (float*)alloc(N_E*4);
    float* el4 = (float*)alloc(N_E*4);  float* er5 = (float*)alloc(N_E*4);
    float* er4 = (float*)alloc(N_U*4);  float* el5 = (float*)alloc(N_U*4);
    int* cnt  = (int*)alloc((size_t)N_TOT*4);
    int* offA = (int*)alloc((size_t)N_TOT*4);
    int* cur  = (int*)alloc((size_t)N_TOT*4);
    int* bsum = (int*)alloc(1024*4);
    int* sorted = (int*)alloc((size_t)E_TOT*4);
    u16* agg  = (u16*)alloc((size_t)PTOT*128*2);
    u16* gout = (u16*)alloc((size_t)GTOT*128*2);
    size_t need_base = off_b;
    u16* knb   = (u16*)alloc((size_t)N_K*128*2);
    u16* exerb = (u16*)alloc((size_t)N_E*128*2);
    u16* stub  = (u16*)alloc((size_t)N_U*128*2);
    size_t need_bf = off_b;
    bool useBF = (ws_size >= need_bf);      // bf16-gather path needs ~155 MB; base ~111 MB
    (void)need_base;
    float* out = (float*)d_out;

    const int NBLK = (N_TOT + 255)/256;     // 938 (<=1024 for scan2)

    hipMemsetAsync(cnt, 0, (size_t)N_TOT*4, stream);

    prep_vecs<<<10,128,0,stream>>>(W_und,W_ek,W_ke,W_eu,W_ue, a_und,a_ek,a_ke,a_eu,a_ue, vecs);
    fragify<<<5,256,0,stream>>>(W_und,W_ek,W_ke,W_eu,W_ue, Wf);

    // el/er for all 5 GATs; wl_g = vecs+g*128, wr_g = vecs+(5+g)*128; g: 0=und 1=ek 2=ke 3=eu 4=ue
    dot4<<<(N_K+3)/4,256,0,stream>>>(kn,   vecs+0,    vecs+640, vecs+768,  vecs+256,  el1,er1,er2,el3, N_K);
    dot4<<<(N_E+3)/4,256,0,stream>>>(exer, vecs+128,  vecs+896, vecs+384,  vecs+1152, el2,er3,el4,er5, N_E);
    dot2<<<(N_U+3)/4,256,0,stream>>>(stu,  vecs+1024, vecs+512, er4, el5, N_U);

    count_all<<<(E_TOT+255)/256,256,0,stream>>>(und_dst, ek_src, ek_dst, eu_src, eu_dst, cnt);
    scan1<<<NBLK,256,0,stream>>>(cnt, offA, bsum, N_TOT);
    scan2<<<1,1024,0,stream>>>(bsum, NBLK);
    scan3<<<NBLK,256,0,stream>>>(offA, cur, bsum, N_TOT);
    fill_all<<<(E_TOT+255)/256,256,0,stream>>>(und_src, und_dst, ek_src, ek_dst, eu_src, eu_dst, cur, sorted);

    if (useBF){
        convbf<<<(N_K*32+255)/256,256,0,stream>>>(kn,   knb,   N_K*32);
        convbf<<<(N_E*32+255)/256,256,0,stream>>>(exer, exerb, N_E*32);
        convbf<<<(N_U*32+255)/256,256,0,stream>>>(stu,  stub,  N_U*32);
        aggregate_all<1><<<(PTOT+3)/4,256,0,stream>>>(cnt, offA, sorted,
            el1,el2,el3,el4,el5, er1,er2,er3,er4,er5, knb, exerb, stub, agg);
    } else {
        aggregate_all<0><<<(PTOT+3)/4,256,0,stream>>>(cnt, offA, sorted,
            el1,el2,el3,el4,el5, er1,er2,er3,er4,er5, kn, exer, stu, agg);
    }

    gemm_all<<<PTOT/64,256,0,stream>>>(agg, Wf, gout, out + (size_t)(N_K+N_E)*128, stu);

    fuse_epi<<<(N_K+3)/4,256,0,stream>>>(kn,   gout + (size_t)PB1*128, gout + (size_t)PB2*128,
                                         kfc2w,kfc2b,kfc3w,kfc3b, out, N_K);
    fuse_epi<<<(N_E+3)/4,256,0,stream>>>(exer, gout + (size_t)PB3*128, gout + (size_t)GB5*128,
                                         efc1w,efc1b,efc2w,efc2b, out + (size_t)N_K*128, N_E);
}

// Round 4
// 507.694 us; speedup vs baseline: 1.2652x; 1.2652x over previous
//
#include <hip/hip_runtime.h>

#define N_K 20000
#define N_E 50000
#define N_U 100000
#define E_UND 200000
#define E_EK 400000
#define E_EU 600000
#define E_TOT 2200000
#define N_TOT 240000
// padded (64-aligned) agg-row segment bases: GAT1 kn | GAT2 kn | GAT3 exer | GAT4 stu | GAT5 exer
#define PB1 0
#define PB2 20032
#define PB3 40064
#define PB4 90112
#define PB5 190144
#define PTOT 240192
// gout compact bases (seg 3 = student goes straight to d_out)
#define GB5 90112
#define GTOT 140160

typedef unsigned short u16;
typedef unsigned int u32;
typedef __bf16 bf16x8 __attribute__((ext_vector_type(8)));
typedef float f32x4 __attribute__((ext_vector_type(4)));

__device__ __forceinline__ float bf2f(u16 v){
    union { u32 u; float f; } x; x.u = ((u32)v) << 16; return x.f;
}
__device__ __forceinline__ u16 f2bf(float f){
    union { float f; u32 u; } x; x.f = f;
    u32 r = x.u + 0x7FFFu + ((x.u >> 16) & 1u);
    return (u16)(r >> 16);
}

// ---------------------------------------------------------------- prep: wl/wr
// wl_g = W_g @ a_g[:128] at vecs+g*128 ; wr_g = W_g @ a_g[128:] at vecs+(5+g)*128
__global__ void prep_vecs(const float* W0, const float* W1, const float* W2, const float* W3, const float* W4,
                          const float* a0, const float* a1, const float* a2, const float* a3, const float* a4,
                          float* __restrict__ vecs)
{
    int b = blockIdx.x;          // 0..9
    int g = b % 5, which = b / 5;
    const float* W = g==0?W0:g==1?W1:g==2?W2:g==3?W3:W4;
    const float* a = g==0?a0:g==1?a1:g==2?a2:g==3?a3:a4;
    const float* av = a + which*128;
    int k = threadIdx.x;         // 0..127
    float sum = 0.f;
    for (int c = 0; c < 128; ++c)
        sum += W[k*128 + c] * av[c];
    vecs[(which*5 + g)*128 + k] = sum;
}

// -------------------------------------------- W -> MFMA-B-fragment order (bf16)
// B frag of mfma_f32_16x16x32_bf16: lane l holds B[k][n], n=ct*16+(l&15),
// k = ks*32 + (l>>4)*8 + j. Linear frag index t = ct*4+ks.
__global__ void fragify(const float* W0, const float* W1, const float* W2, const float* W3, const float* W4,
                        u16* __restrict__ Wf)
{
    int g = blockIdx.x;
    const float* W = g==0?W0:g==1?W1:g==2?W2:g==3?W3:W4;
    u16* out = Wf + g*16384;
    for (int i = threadIdx.x; i < 2048; i += blockDim.x){
        int lane = i & 63, t = i >> 6, ks = t & 3, ct = t >> 2;
        int kbase = ks*32 + (lane>>4)*8;
        int c = ct*16 + (lane&15);
        #pragma unroll
        for (int j = 0; j < 8; ++j)
            out[i*8 + j] = f2bf(W[(kbase+j)*128 + c]);
    }
}

// ------------------------------------------------- fused conv(f32->bf16) + row dots
// One wave per row. Reads the f32 embedding row once; computes ND dot products
// against v0..v3; optionally (WBF) writes the bf16 row for the gather stage.
template<int ND, int WBF>
__global__ __launch_bounds__(256) void conv_dot(const float* __restrict__ h, u16* __restrict__ hb,
    const float* __restrict__ v0, const float* __restrict__ v1,
    const float* __restrict__ v2, const float* __restrict__ v3,
    float* __restrict__ o0, float* __restrict__ o1,
    float* __restrict__ o2, float* __restrict__ o3, int nrows)
{
    int w = (int)((blockIdx.x*(u32)blockDim.x + threadIdx.x) >> 6);
    int lane = threadIdx.x & 63;
    if (w >= nrows) return;
    float2 hv = *(const float2*)(h + (size_t)w*128 + lane*2);
    if (WBF)
        *(u32*)(hb + (size_t)w*128 + lane*2) = (u32)f2bf(hv.x) | ((u32)f2bf(hv.y) << 16);
    int c = lane*2;
    float d0 = hv.x*v0[c] + hv.y*v0[c+1];
    float d1 = hv.x*v1[c] + hv.y*v1[c+1];
    float d2 = 0.f, d3 = 0.f;
    if (ND == 4){
        d2 = hv.x*v2[c] + hv.y*v2[c+1];
        d3 = hv.x*v3[c] + hv.y*v3[c+1];
    }
    #pragma unroll
    for (int o = 32; o; o >>= 1){
        d0 += __shfl_xor(d0, o); d1 += __shfl_xor(d1, o);
        if (ND == 4){ d2 += __shfl_xor(d2, o); d3 += __shfl_xor(d3, o); }
    }
    if (lane == 0){
        o0[w] = d0; o1[w] = d1;
        if (ND == 4){ o2[w] = d2; o3[w] = d3; }
    }
}

// ------------------------------------------------- CSR build (all 5 graphs fused)
__global__ void count_all(const int* __restrict__ ud,
                          const int* __restrict__ es, const int* __restrict__ ed,
                          const int* __restrict__ vs, const int* __restrict__ vd,
                          int* __restrict__ cnt)
{
    int e = blockIdx.x*256 + threadIdx.x;
    if (e >= E_TOT) return;
    int dstv, nb;
    if (e < 200000){ dstv = ud[e]; nb = 0; }
    else if (e < 600000){ dstv = ed[e-200000]; nb = 20000; }
    else if (e < 1000000){ dstv = es[e-600000]; nb = 40000; }
    else if (e < 1600000){ dstv = vd[e-1000000]; nb = 90000; }
    else { dstv = vs[e-1600000]; nb = 190000; }
    atomicAdd(&cnt[nb + dstv], 1);
}

__global__ void fill_all(const int* __restrict__ us, const int* __restrict__ ud,
                         const int* __restrict__ es, const int* __restrict__ ed,
                         const int* __restrict__ vs, const int* __restrict__ vd,
                         int* __restrict__ cur, int* __restrict__ sorted)
{
    int e = blockIdx.x*256 + threadIdx.x;
    if (e >= E_TOT) return;
    int srcv, dstv, nb;
    if (e < 200000){ srcv = us[e]; dstv = ud[e]; nb = 0; }
    else if (e < 600000){ int i=e-200000; srcv = es[i]; dstv = ed[i]; nb = 20000; }
    else if (e < 1000000){ int i=e-600000; srcv = ed[i]; dstv = es[i]; nb = 40000; }
    else if (e < 1600000){ int i=e-1000000; srcv = vs[i]; dstv = vd[i]; nb = 90000; }
    else { int i=e-1600000; srcv = vd[i]; dstv = vs[i]; nb = 190000; }
    int pos = atomicAdd(&cur[nb + dstv], 1);
    sorted[pos] = srcv;
}

// block-level exclusive scan (Hillis-Steele in LDS)
__global__ void scan1(const int* __restrict__ cnt, int* __restrict__ off, int* __restrict__ bsum, int n){
    __shared__ int sm[256];
    int t = threadIdx.x;
    int i = blockIdx.x*256 + t;
    int v = (i < n) ? cnt[i] : 0;
    sm[t] = v; __syncthreads();
    #pragma unroll
    for (int d = 1; d < 256; d <<= 1){
        int x = (t >= d) ? sm[t-d] : 0;
        __syncthreads();
        sm[t] += x;
        __syncthreads();
    }
    if (i < n) off[i] = sm[t] - v;
    if (t == 255) bsum[blockIdx.x] = sm[255];
}

__global__ void scan2(int* __restrict__ bsum, int nb){
    __shared__ int sm[1024];
    int t = threadIdx.x;
    int v = (t < nb) ? bsum[t] : 0;
    sm[t] = v; __syncthreads();
    #pragma unroll
    for (int d = 1; d < 1024; d <<= 1){
        int x = (t >= d) ? sm[t-d] : 0;
        __syncthreads();
        sm[t] += x;
        __syncthreads();
    }
    if (t < nb) bsum[t] = sm[t] - v;
}

__global__ void scan3(int* __restrict__ off, int* __restrict__ cur, const int* __restrict__ bsum, int n){
    int i = blockIdx.x*256 + threadIdx.x;
    if (i < n){
        int v = off[i] + bsum[blockIdx.x];
        off[i] = v;
        cur[i] = v;
    }
}

// ------------------------------------------------- fused GAT aggregation (wave per dst node)
// agg[d] = (sum_e ev*h[src_e]) / (sum_e ev), ev = exp(leaky(el[src_e]+er[d])).
// Unrolled x4: 4 independent edge streams in flight (latency-bound fix, r4).
// max-shift skipped: el+er ~ N(0,2) -> exp safe; softmax shift-invariant.
__device__ __forceinline__ float leaky_exp(float x){
    x = x >= 0.f ? x : 0.01f*x;
    return __expf(x);
}

template<int BF>
__global__ __launch_bounds__(256) void aggregate_all(
    const int* __restrict__ cnt, const int* __restrict__ off, const int* __restrict__ sorted,
    const float* __restrict__ el1, const float* __restrict__ el2, const float* __restrict__ el3,
    const float* __restrict__ el4, const float* __restrict__ el5,
    const float* __restrict__ er1, const float* __restrict__ er2, const float* __restrict__ er3,
    const float* __restrict__ er4, const float* __restrict__ er5,
    const void* __restrict__ hk, const void* __restrict__ he, const void* __restrict__ hs,
    u16* __restrict__ agg)
{
    int row = (int)((blockIdx.x*(u32)blockDim.x + threadIdx.x) >> 6);
    int lane = threadIdx.x & 63;
    if (row >= PTOT) return;
    int local, nb, sn;
    const float *el, *er;
    const void* h;
    if (row < PB2){ local=row;      nb=0;      sn=N_K; el=el1; er=er1; h=hk; }
    else if (row < PB3){ local=row-PB2; nb=20000;  sn=N_K; el=el2; er=er2; h=he; }
    else if (row < PB4){ local=row-PB3; nb=40000;  sn=N_E; el=el3; er=er3; h=hk; }
    else if (row < PB5){ local=row-PB4; nb=90000;  sn=N_U; el=el4; er=er4; h=he; }
    else {              local=row-PB5; nb=190000; sn=N_E; el=el5; er=er5; h=hs; }
    if (local >= sn) return;   // 64-pad tail
    int ci = nb + local;
    int deg = cnt[ci], start = off[ci];
    float erd = er[local];
    float a0 = 0.f, a1 = 0.f, ssum = 0.f;
    const u32* hb32 = (const u32*)h;
    const float2* hf2 = (const float2*)h;
    int i = 0;
    for (; i + 4 <= deg; i += 4){
        int s0 = sorted[start+i+0], s1 = sorted[start+i+1];
        int s2 = sorted[start+i+2], s3 = sorted[start+i+3];
        float e0 = leaky_exp(el[s0] + erd);
        float e1 = leaky_exp(el[s1] + erd);
        float e2 = leaky_exp(el[s2] + erd);
        float e3 = leaky_exp(el[s3] + erd);
        if (BF){
            u32 h0 = hb32[(size_t)s0*64 + lane];
            u32 h1 = hb32[(size_t)s1*64 + lane];
            u32 h2 = hb32[(size_t)s2*64 + lane];
            u32 h3 = hb32[(size_t)s3*64 + lane];
            a0 = fmaf(e0, bf2f((u16)h0), a0); a1 = fmaf(e0, bf2f((u16)(h0>>16)), a1);
            a0 = fmaf(e1, bf2f((u16)h1), a0); a1 = fmaf(e1, bf2f((u16)(h1>>16)), a1);
            a0 = fmaf(e2, bf2f((u16)h2), a0); a1 = fmaf(e2, bf2f((u16)(h2>>16)), a1);
            a0 = fmaf(e3, bf2f((u16)h3), a0); a1 = fmaf(e3, bf2f((u16)(h3>>16)), a1);
        } else {
            float2 h0 = hf2[(size_t)s0*64 + lane];
            float2 h1 = hf2[(size_t)s1*64 + lane];
            float2 h2 = hf2[(size_t)s2*64 + lane];
            float2 h3 = hf2[(size_t)s3*64 + lane];
            a0 = fmaf(e0, h0.x, a0); a1 = fmaf(e0, h0.y, a1);
            a0 = fmaf(e1, h1.x, a0); a1 = fmaf(e1, h1.y, a1);
            a0 = fmaf(e2, h2.x, a0); a1 = fmaf(e2, h2.y, a1);
            a0 = fmaf(e3, h3.x, a0); a1 = fmaf(e3, h3.y, a1);
        }
        ssum += (e0 + e1) + (e2 + e3);
    }
    for (; i < deg; ++i){
        int si = sorted[start + i];
        float ev = leaky_exp(el[si] + erd);
        float x0, x1;
        if (BF){
            u32 hv = hb32[(size_t)si*64 + lane];
            x0 = bf2f((u16)hv); x1 = bf2f((u16)(hv>>16));
        } else {
            float2 hv = hf2[(size_t)si*64 + lane];
            x0 = hv.x; x1 = hv.y;
        }
        a0 = fmaf(ev, x0, a0);
        a1 = fmaf(ev, x1, a1);
        ssum += ev;
    }
    float inv = (ssum > 0.f) ? 1.f/ssum : 0.f;   // deg==0 -> zero row (matches reference)
    *(u32*)(agg + (size_t)row*128 + lane*2) = (u32)f2bf(a0*inv) | ((u32)f2bf(a1*inv) << 16);
}

// ------------------------------------------------- fused agg(bf16) @ W_g
// segs 0,1,2,4 -> bf16 gout (compact padded layout); seg 3 (student) -> f32 d_out + resid
__global__ __launch_bounds__(256) void gemm_all(const u16* __restrict__ agg, const u16* __restrict__ Wf,
    u16* __restrict__ gout, float* __restrict__ outstu, const float* __restrict__ resid)
{
    int wave = threadIdx.x >> 6, lane = threadIdx.x & 63;
    int rowbase = blockIdx.x*64 + wave*16;
    int segbase, sn, g, gb;
    if (rowbase < PB2){ segbase=PB1; sn=N_K; g=0; gb=PB1; }
    else if (rowbase < PB3){ segbase=PB2; sn=N_K; g=1; gb=PB2; }
    else if (rowbase < PB4){ segbase=PB3; sn=N_E; g=2; gb=PB3; }
    else if (rowbase < PB5){ segbase=PB4; sn=N_U; g=3; gb=-1; }
    else { segbase=PB5; sn=N_E; g=4; gb=GB5; }
    int local0 = rowbase - segbase;
    if (local0 >= sn) return;   // pad chunk (sn % 16 == 0, so surviving waves are fully real)
    const u16* ap = agg + (size_t)(rowbase + (lane & 15))*128 + ((lane>>4)*8);
    bf16x8 afrag[4];
    #pragma unroll
    for (int ks = 0; ks < 4; ++ks)
        afrag[ks] = *(const bf16x8*)(ap + ks*32);
    const u16* wfp = Wf + g*16384;
    f32x4 acc[8];
    #pragma unroll
    for (int ct = 0; ct < 8; ++ct) acc[ct] = (f32x4){0.f,0.f,0.f,0.f};
    #pragma unroll
    for (int ks = 0; ks < 4; ++ks){
        #pragma unroll
        for (int ct = 0; ct < 8; ++ct){
            bf16x8 b = *(const bf16x8*)(wfp + ((size_t)((ct*4+ks)*64 + lane))*8);
            acc[ct] = __builtin_amdgcn_mfma_f32_16x16x32_bf16(afrag[ks], b, acc[ct], 0, 0, 0);
        }
    }
    int rlo = (lane>>4)*4;
    int colb = lane & 15;
    if (g == 3){
        #pragma unroll
        for (int ct = 0; ct < 8; ++ct){
            #pragma unroll
            for (int j = 0; j < 4; ++j){
                size_t idx = (size_t)(local0 + rlo + j)*128 + ct*16 + colb;
                outstu[idx] = acc[ct][j] + resid[idx];
            }
        }
    } else {
        #pragma unroll
        for (int ct = 0; ct < 8; ++ct){
            #pragma unroll
            for (int j = 0; j < 4; ++j){
                size_t idx = (size_t)(gb + local0 + rlo + j)*128 + ct*16 + colb;
                gout[idx] = f2bf(acc[ct][j]);
            }
        }
    }
}

// ------------------------------------------------- gating epilogue (kn & exer), f32 out
__global__ __launch_bounds__(256) void fuse_epi(const float* __restrict__ A,
    const u16* __restrict__ C, const u16* __restrict__ D,
    const float* __restrict__ w2, const float* __restrict__ b2,
    const float* __restrict__ w3, const float* __restrict__ b3,
    float* __restrict__ outp, int n)
{
    int w = (int)((blockIdx.x*(u32)blockDim.x + threadIdx.x) >> 6);
    int lane = threadIdx.x & 63;
    if (w >= n) return;
    int c = lane*2;
    float2 av = *(const float2*)(A + (size_t)w*128 + c);
    u32 cv = *(const u32*)(C + (size_t)w*128 + c);
    u32 dv = *(const u32*)(D + (size_t)w*128 + c);
    float c0 = bf2f((u16)cv), c1 = bf2f((u16)(cv>>16));
    float d0 = bf2f((u16)dv), d1 = bf2f((u16)(dv>>16));
    float s2 = av.x*w2[c] + av.y*w2[c+1] + c0*w2[128+c] + c1*w2[128+c+1];
    float s3 = av.x*w3[c] + av.y*w3[c+1] + d0*w3[128+c] + d1*w3[128+c+1];
    #pragma unroll
    for (int o = 32; o; o >>= 1){ s2 += __shfl_xor(s2, o); s3 += __shfl_xor(s3, o); }
    s2 += b2[0]; s3 += b3[0];
    float m = fmaxf(s2, s3);
    float e2 = __expf(s2 - m), e3 = __expf(s3 - m);
    float inv = 1.f/(e2 + e3);
    float p2 = e2*inv, p3 = e3*inv;
    float2 r;
    r.x = av.x + p2*c0 + p3*d0;
    r.y = av.y + p2*c1 + p3*d1;
    *(float2*)(outp + (size_t)w*128 + c) = r;
}

extern "C" void kernel_launch(void* const* d_in, const int* in_sizes, int n_in,
                              void* d_out, int out_size, void* d_ws, size_t ws_size,
                              hipStream_t stream)
{
    (void)in_sizes; (void)n_in; (void)out_size;
    const float* kn   = (const float*)d_in[0];
    const float* exer = (const float*)d_in[1];
    const float* stu  = (const float*)d_in[2];
    const int* und_src = (const int*)d_in[3];
    const int* und_dst = (const int*)d_in[4];
    const int* ek_src  = (const int*)d_in[5];
    const int* ek_dst  = (const int*)d_in[6];
    const int* eu_src  = (const int*)d_in[7];
    const int* eu_dst  = (const int*)d_in[8];
    const float* W_und = (const float*)d_in[9];  const float* a_und = (const float*)d_in[10];
    const float* W_ek  = (const float*)d_in[11]; const float* a_ek  = (const float*)d_in[12];
    const float* W_ke  = (const float*)d_in[13]; const float* a_ke  = (const float*)d_in[14];
    const float* W_eu  = (const float*)d_in[15]; const float* a_eu  = (const float*)d_in[16];
    const float* W_ue  = (const float*)d_in[17]; const float* a_ue  = (const float*)d_in[18];
    const float* kfc2w = (const float*)d_in[19]; const float* kfc2b = (const float*)d_in[20];
    const float* kfc3w = (const float*)d_in[21]; const float* kfc3b = (const float*)d_in[22];
    const float* efc1w = (const float*)d_in[23]; const float* efc1b = (const float*)d_in[24];
    const float* efc2w = (const float*)d_in[25]; const float* efc2b = (const float*)d_in[26];

    char* base = (char*)d_ws;
    size_t off_b = 0;
    auto alloc = [&](size_t bytes)->char*{
        char* p = base + off_b;
        off_b += (bytes + 255) & ~(size_t)255;
        return p;
    };
    float* vecs = (float*)alloc(1280*4);
    u16*   Wf   = (u16*)  alloc(5*16384*2);
    float* el1 = (float*)alloc(N_K*4);  float* er1 = (float*)alloc(N_K*4);
    float* er2 = (float*)alloc(N_K*4);  float* el3 = (float*)alloc(N_K*4);
    float* el2 = (float*)alloc(N_E*4);  float* er3 = (float*)alloc(N_E*4);
    float* el4 = (float*)alloc(N_E*4);  float* er5 = (float*)alloc(N_E*4);
    float* er4 = (float*)alloc(N_U*4);  float* el5 = (float*)alloc(N_U*4);
    int* cnt  = (int*)alloc((size_t)N_TOT*4);
    int* offA = (int*)alloc((size_t)N_TOT*4);
    int* cur  = (int*)alloc((size_t)N_TOT*4);
    int* bsum = (int*)alloc(1024*4);
    int* sorted = (int*)alloc((size_t)E_TOT*4);
    u16* agg  = (u16*)alloc((size_t)PTOT*128*2);
    u16* gout = (u16*)alloc((size_t)GTOT*128*2);
    u16* knb   = (u16*)alloc((size_t)N_K*128*2);
    u16* exerb = (u16*)alloc((size_t)N_E*128*2);
    u16* stub  = (u16*)alloc((size_t)N_U*128*2);
    size_t need_bf = off_b;
    bool useBF = (ws_size >= need_bf);      // bf16-gather path needs ~155 MB total
    float* out = (float*)d_out;

    const int NBLK = (N_TOT + 255)/256;     // 938 (<=1024 for scan2)

    hipMemsetAsync(cnt, 0, (size_t)N_TOT*4, stream);

    prep_vecs<<<10,128,0,stream>>>(W_und,W_ek,W_ke,W_eu,W_ue, a_und,a_ek,a_ke,a_eu,a_ue, vecs);
    fragify<<<5,256,0,stream>>>(W_und,W_ek,W_ke,W_eu,W_ue, Wf);

    // fused conv(f32->bf16) + el/er dots; wl_g = vecs+g*128, wr_g = vecs+(5+g)*128
    // g: 0=und 1=ek 2=ke 3=eu 4=ue
    if (useBF){
        conv_dot<4,1><<<(N_K+3)/4,256,0,stream>>>(kn,   knb,   vecs+0,    vecs+640, vecs+768,  vecs+256,  el1,er1,er2,el3, N_K);
        conv_dot<4,1><<<(N_E+3)/4,256,0,stream>>>(exer, exerb, vecs+128,  vecs+896, vecs+384,  vecs+1152, el2,er3,el4,er5, N_E);
        conv_dot<2,1><<<(N_U+3)/4,256,0,stream>>>(stu,  stub,  vecs+1024, vecs+512, nullptr, nullptr, er4, el5, nullptr, nullptr, N_U);
    } else {
        conv_dot<4,0><<<(N_K+3)/4,256,0,stream>>>(kn,   nullptr, vecs+0,    vecs+640, vecs+768,  vecs+256,  el1,er1,er2,el3, N_K);
        conv_dot<4,0><<<(N_E+3)/4,256,0,stream>>>(exer, nullptr, vecs+128,  vecs+896, vecs+384,  vecs+1152, el2,er3,el4,er5, N_E);
        conv_dot<2,0><<<(N_U+3)/4,256,0,stream>>>(stu,  nullptr, vecs+1024, vecs+512, nullptr, nullptr, er4, el5, nullptr, nullptr, N_U);
    }

    count_all<<<(E_TOT+255)/256,256,0,stream>>>(und_dst, ek_src, ek_dst, eu_src, eu_dst, cnt);
    scan1<<<NBLK,256,0,stream>>>(cnt, offA, bsum, N_TOT);
    scan2<<<1,1024,0,stream>>>(bsum, NBLK);
    scan3<<<NBLK,256,0,stream>>>(offA, cur, bsum, N_TOT);
    fill_all<<<(E_TOT+255)/256,256,0,stream>>>(und_src, und_dst, ek_src, ek_dst, eu_src, eu_dst, cur, sorted);

    if (useBF){
        aggregate_all<1><<<(PTOT+3)/4,256,0,stream>>>(cnt, offA, sorted,
            el1,el2,el3,el4,el5, er1,er2,er3,er4,er5, knb, exerb, stub, agg);
    } else {
        aggregate_all<0><<<(PTOT+3)/4,256,0,stream>>>(cnt, offA, sorted,
            el1,el2,el3,el4,el5, er1,er2,er3,er4,er5, kn, exer, stu, agg);
    }

    gemm_all<<<PTOT/64,256,0,stream>>>(agg, Wf, gout, out + (size_t)(N_K+N_E)*128, stu);

    fuse_epi<<<(N_K+3)/4,256,0,stream>>>(kn,   gout + (size_t)PB1*128, gout + (size_t)PB2*128,
                                         kfc2w,kfc2b,kfc3w,kfc3b, out, N_K);
    fuse_epi<<<(N_E+3)/4,256,0,stream>>>(exer, gout + (size_t)PB3*128, gout + (size_t)GB5*128,
                                         efc1w,efc1b,efc2w,efc2b, out + (size_t)N_K*128, N_E);
}

// Round 5
// 482.299 us; speedup vs baseline: 1.3318x; 1.0527x over previous
//
#include <hip/hip_runtime.h>

#define N_K 20000
#define N_E 50000
#define N_U 100000
#define E_UND 200000
#define E_EK 400000
#define E_EU 600000
#define E_TOT 2200000
#define N_TOT 240000
// padded (64-aligned) agg-row segment bases: GAT1 kn | GAT2 kn | GAT3 exer | GAT4 stu | GAT5 exer
#define PB1 0
#define PB2 20032
#define PB3 40064
#define PB4 90112
#define PB5 190144
#define PTOT 240192
// gout compact bases (seg 3 = student goes straight to d_out)
#define GB5 90112
#define GTOT 140160

typedef unsigned short u16;
typedef unsigned int u32;
typedef __bf16 bf16x8 __attribute__((ext_vector_type(8)));
typedef float f32x4 __attribute__((ext_vector_type(4)));

__device__ __forceinline__ float bf2f(u16 v){
    union { u32 u; float f; } x; x.u = ((u32)v) << 16; return x.f;
}
__device__ __forceinline__ u16 f2bf(float f){
    union { float f; u32 u; } x; x.f = f;
    u32 r = x.u + 0x7FFFu + ((x.u >> 16) & 1u);
    return (u16)(r >> 16);
}

// ---------------------------------------------------------------- prep: wl/wr
// wl_g = W_g @ a_g[:128] at vecs+g*128 ; wr_g = W_g @ a_g[128:] at vecs+(5+g)*128
__global__ void prep_vecs(const float* W0, const float* W1, const float* W2, const float* W3, const float* W4,
                          const float* a0, const float* a1, const float* a2, const float* a3, const float* a4,
                          float* __restrict__ vecs)
{
    int b = blockIdx.x;          // 0..9
    int g = b % 5, which = b / 5;
    const float* W = g==0?W0:g==1?W1:g==2?W2:g==3?W3:W4;
    const float* a = g==0?a0:g==1?a1:g==2?a2:g==3?a3:a4;
    const float* av = a + which*128;
    int k = threadIdx.x;         // 0..127
    float sum = 0.f;
    for (int c = 0; c < 128; ++c)
        sum += W[k*128 + c] * av[c];
    vecs[(which*5 + g)*128 + k] = sum;
}

// -------------------------------------------- W -> MFMA-B-fragment order (bf16)
// B frag of mfma_f32_16x16x32_bf16: lane l holds B[k][n], n=ct*16+(l&15),
// k = ks*32 + (l>>4)*8 + j. Linear frag index t = ct*4+ks.
__global__ void fragify(const float* W0, const float* W1, const float* W2, const float* W3, const float* W4,
                        u16* __restrict__ Wf)
{
    int g = blockIdx.x;
    const float* W = g==0?W0:g==1?W1:g==2?W2:g==3?W3:W4;
    u16* out = Wf + g*16384;
    for (int i = threadIdx.x; i < 2048; i += blockDim.x){
        int lane = i & 63, t = i >> 6, ks = t & 3, ct = t >> 2;
        int kbase = ks*32 + (lane>>4)*8;
        int c = ct*16 + (lane&15);
        #pragma unroll
        for (int j = 0; j < 8; ++j)
            out[i*8 + j] = f2bf(W[(kbase+j)*128 + c]);
    }
}

// ------------------------------------------------- fused conv(f32->bf16) + row dots
template<int ND, int WBF>
__global__ __launch_bounds__(256) void conv_dot(const float* __restrict__ h, u16* __restrict__ hb,
    const float* __restrict__ v0, const float* __restrict__ v1,
    const float* __restrict__ v2, const float* __restrict__ v3,
    float* __restrict__ o0, float* __restrict__ o1,
    float* __restrict__ o2, float* __restrict__ o3, int nrows)
{
    int w = (int)((blockIdx.x*(u32)blockDim.x + threadIdx.x) >> 6);
    int lane = threadIdx.x & 63;
    if (w >= nrows) return;
    float2 hv = *(const float2*)(h + (size_t)w*128 + lane*2);
    if (WBF)
        *(u32*)(hb + (size_t)w*128 + lane*2) = (u32)f2bf(hv.x) | ((u32)f2bf(hv.y) << 16);
    int c = lane*2;
    float d0 = hv.x*v0[c] + hv.y*v0[c+1];
    float d1 = hv.x*v1[c] + hv.y*v1[c+1];
    float d2 = 0.f, d3 = 0.f;
    if (ND == 4){
        d2 = hv.x*v2[c] + hv.y*v2[c+1];
        d3 = hv.x*v3[c] + hv.y*v3[c+1];
    }
    #pragma unroll
    for (int o = 32; o; o >>= 1){
        d0 += __shfl_xor(d0, o); d1 += __shfl_xor(d1, o);
        if (ND == 4){ d2 += __shfl_xor(d2, o); d3 += __shfl_xor(d3, o); }
    }
    if (lane == 0){
        o0[w] = d0; o1[w] = d1;
        if (ND == 4){ o2[w] = d2; o3[w] = d3; }
    }
}

// ------------------------------------------------- CSR build (all 5 graphs fused)
__global__ void count_all(const int* __restrict__ ud,
                          const int* __restrict__ es, const int* __restrict__ ed,
                          const int* __restrict__ vs, const int* __restrict__ vd,
                          int* __restrict__ cnt)
{
    int e = blockIdx.x*256 + threadIdx.x;
    if (e >= E_TOT) return;
    int dstv, nb;
    if (e < 200000){ dstv = ud[e]; nb = 0; }
    else if (e < 600000){ dstv = ed[e-200000]; nb = 20000; }
    else if (e < 1000000){ dstv = es[e-600000]; nb = 40000; }
    else if (e < 1600000){ dstv = vd[e-1000000]; nb = 90000; }
    else { dstv = vs[e-1600000]; nb = 190000; }
    atomicAdd(&cnt[nb + dstv], 1);
}

// range-partitioned fill: pass handles keys in [klo,khi) only, so the write
// region of `sorted` (and the hot slice of cur) is ~2.2 MB -> L2-resident.
// Fix for r4's 133 MB WRITE_SIZE (one 64B line writeback per random 4B store).
__global__ void fill_all(const int* __restrict__ us, const int* __restrict__ ud,
                         const int* __restrict__ es, const int* __restrict__ ed,
                         const int* __restrict__ vs, const int* __restrict__ vd,
                         int* __restrict__ cur, int* __restrict__ sorted,
                         int klo, int khi)
{
    int e = blockIdx.x*256 + threadIdx.x;
    if (e >= E_TOT) return;
    int dstv, nb;
    if (e < 200000){ dstv = ud[e]; nb = 0; }
    else if (e < 600000){ dstv = ed[e-200000]; nb = 20000; }
    else if (e < 1000000){ dstv = es[e-600000]; nb = 40000; }
    else if (e < 1600000){ dstv = vd[e-1000000]; nb = 90000; }
    else { dstv = vs[e-1600000]; nb = 190000; }
    int key = nb + dstv;
    if (key < klo || key >= khi) return;
    int srcv;
    if (e < 200000){ srcv = us[e]; }
    else if (e < 600000){ srcv = es[e-200000]; }
    else if (e < 1000000){ srcv = ed[e-600000]; }
    else if (e < 1600000){ srcv = vs[e-1000000]; }
    else { srcv = vd[e-1600000]; }
    int pos = atomicAdd(&cur[key], 1);
    sorted[pos] = srcv;
}

// block-level exclusive scan (Hillis-Steele in LDS)
__global__ void scan1(const int* __restrict__ cnt, int* __restrict__ off, int* __restrict__ bsum, int n){
    __shared__ int sm[256];
    int t = threadIdx.x;
    int i = blockIdx.x*256 + t;
    int v = (i < n) ? cnt[i] : 0;
    sm[t] = v; __syncthreads();
    #pragma unroll
    for (int d = 1; d < 256; d <<= 1){
        int x = (t >= d) ? sm[t-d] : 0;
        __syncthreads();
        sm[t] += x;
        __syncthreads();
    }
    if (i < n) off[i] = sm[t] - v;
    if (t == 255) bsum[blockIdx.x] = sm[255];
}

__global__ void scan2(int* __restrict__ bsum, int nb){
    __shared__ int sm[1024];
    int t = threadIdx.x;
    int v = (t < nb) ? bsum[t] : 0;
    sm[t] = v; __syncthreads();
    #pragma unroll
    for (int d = 1; d < 1024; d <<= 1){
        int x = (t >= d) ? sm[t-d] : 0;
        __syncthreads();
        sm[t] += x;
        __syncthreads();
    }
    if (t < nb) bsum[t] = sm[t] - v;
}

__global__ void scan3(int* __restrict__ off, int* __restrict__ cur, const int* __restrict__ bsum, int n){
    int i = blockIdx.x*256 + threadIdx.x;
    if (i < n){
        int v = off[i] + bsum[blockIdx.x];
        off[i] = v;
        cur[i] = v;
    }
}

// ------------------------------------------------- fused GAT aggregation (wave per dst node)
// agg[d] = (sum_e ev*h[src_e]) / (sum_e ev), ev = exp(leaky(el[src_e]+er[d])).
// 8/4/1 unroll ladder: up to 8 independent edge streams in flight.
// max-shift skipped: el+er ~ N(0,2) -> exp safe; softmax shift-invariant.
__device__ __forceinline__ float leaky_exp(float x){
    x = x >= 0.f ? x : 0.01f*x;
    return __expf(x);
}

template<int BF>
__global__ __launch_bounds__(256) void aggregate_all(
    const int* __restrict__ cnt, const int* __restrict__ off, const int* __restrict__ sorted,
    const float* __restrict__ el1, const float* __restrict__ el2, const float* __restrict__ el3,
    const float* __restrict__ el4, const float* __restrict__ el5,
    const float* __restrict__ er1, const float* __restrict__ er2, const float* __restrict__ er3,
    const float* __restrict__ er4, const float* __restrict__ er5,
    const void* __restrict__ hk, const void* __restrict__ he, const void* __restrict__ hs,
    u16* __restrict__ agg)
{
    int row = (int)((blockIdx.x*(u32)blockDim.x + threadIdx.x) >> 6);
    int lane = threadIdx.x & 63;
    if (row >= PTOT) return;
    int local, nb, sn;
    const float *el, *er;
    const void* h;
    if (row < PB2){ local=row;      nb=0;      sn=N_K; el=el1; er=er1; h=hk; }
    else if (row < PB3){ local=row-PB2; nb=20000;  sn=N_K; el=el2; er=er2; h=he; }
    else if (row < PB4){ local=row-PB3; nb=40000;  sn=N_E; el=el3; er=er3; h=hk; }
    else if (row < PB5){ local=row-PB4; nb=90000;  sn=N_U; el=el4; er=er4; h=he; }
    else {              local=row-PB5; nb=190000; sn=N_E; el=el5; er=er5; h=hs; }
    if (local >= sn) return;   // 64-pad tail
    int ci = nb + local;
    int deg = cnt[ci], start = off[ci];
    float erd = er[local];
    float a0 = 0.f, a1 = 0.f, ssum = 0.f;
    const u32* hb32 = (const u32*)h;
    const float2* hf2 = (const float2*)h;
    int i = 0;
    if (BF){
        for (; i + 8 <= deg; i += 8){
            int s[8]; float e[8]; u32 hv[8];
            #pragma unroll
            for (int j = 0; j < 8; ++j) s[j] = sorted[start+i+j];
            #pragma unroll
            for (int j = 0; j < 8; ++j) e[j] = leaky_exp(el[s[j]] + erd);
            #pragma unroll
            for (int j = 0; j < 8; ++j) hv[j] = hb32[(size_t)s[j]*64 + lane];
            #pragma unroll
            for (int j = 0; j < 8; ++j){
                a0 = fmaf(e[j], bf2f((u16)hv[j]), a0);
                a1 = fmaf(e[j], bf2f((u16)(hv[j]>>16)), a1);
                ssum += e[j];
            }
        }
    }
    for (; i + 4 <= deg; i += 4){
        int s0 = sorted[start+i+0], s1 = sorted[start+i+1];
        int s2 = sorted[start+i+2], s3 = sorted[start+i+3];
        float e0 = leaky_exp(el[s0] + erd);
        float e1 = leaky_exp(el[s1] + erd);
        float e2 = leaky_exp(el[s2] + erd);
        float e3 = leaky_exp(el[s3] + erd);
        if (BF){
            u32 h0 = hb32[(size_t)s0*64 + lane];
            u32 h1 = hb32[(size_t)s1*64 + lane];
            u32 h2 = hb32[(size_t)s2*64 + lane];
            u32 h3 = hb32[(size_t)s3*64 + lane];
            a0 = fmaf(e0, bf2f((u16)h0), a0); a1 = fmaf(e0, bf2f((u16)(h0>>16)), a1);
            a0 = fmaf(e1, bf2f((u16)h1), a0); a1 = fmaf(e1, bf2f((u16)(h1>>16)), a1);
            a0 = fmaf(e2, bf2f((u16)h2), a0); a1 = fmaf(e2, bf2f((u16)(h2>>16)), a1);
            a0 = fmaf(e3, bf2f((u16)h3), a0); a1 = fmaf(e3, bf2f((u16)(h3>>16)), a1);
        } else {
            float2 h0 = hf2[(size_t)s0*64 + lane];
            float2 h1 = hf2[(size_t)s1*64 + lane];
            float2 h2 = hf2[(size_t)s2*64 + lane];
            float2 h3 = hf2[(size_t)s3*64 + lane];
            a0 = fmaf(e0, h0.x, a0); a1 = fmaf(e0, h0.y, a1);
            a0 = fmaf(e1, h1.x, a0); a1 = fmaf(e1, h1.y, a1);
            a0 = fmaf(e2, h2.x, a0); a1 = fmaf(e2, h2.y, a1);
            a0 = fmaf(e3, h3.x, a0); a1 = fmaf(e3, h3.y, a1);
        }
        ssum += (e0 + e1) + (e2 + e3);
    }
    for (; i < deg; ++i){
        int si = sorted[start + i];
        float ev = leaky_exp(el[si] + erd);
        float x0, x1;
        if (BF){
            u32 hv = hb32[(size_t)si*64 + lane];
            x0 = bf2f((u16)hv); x1 = bf2f((u16)(hv>>16));
        } else {
            float2 hv = hf2[(size_t)si*64 + lane];
            x0 = hv.x; x1 = hv.y;
        }
        a0 = fmaf(ev, x0, a0);
        a1 = fmaf(ev, x1, a1);
        ssum += ev;
    }
    float inv = (ssum > 0.f) ? 1.f/ssum : 0.f;   // deg==0 -> zero row (matches reference)
    *(u32*)(agg + (size_t)row*128 + lane*2) = (u32)f2bf(a0*inv) | ((u32)f2bf(a1*inv) << 16);
}

// ------------------------------------------------- fused agg(bf16) @ W_g
// segs 0,1,2,4 -> bf16 gout (compact padded layout); seg 3 (student) -> f32 d_out + resid
__global__ __launch_bounds__(256) void gemm_all(const u16* __restrict__ agg, const u16* __restrict__ Wf,
    u16* __restrict__ gout, float* __restrict__ outstu, const float* __restrict__ resid)
{
    int wave = threadIdx.x >> 6, lane = threadIdx.x & 63;
    int rowbase = blockIdx.x*64 + wave*16;
    int segbase, sn, g, gb;
    if (rowbase < PB2){ segbase=PB1; sn=N_K; g=0; gb=PB1; }
    else if (rowbase < PB3){ segbase=PB2; sn=N_K; g=1; gb=PB2; }
    else if (rowbase < PB4){ segbase=PB3; sn=N_E; g=2; gb=PB3; }
    else if (rowbase < PB5){ segbase=PB4; sn=N_U; g=3; gb=-1; }
    else { segbase=PB5; sn=N_E; g=4; gb=GB5; }
    int local0 = rowbase - segbase;
    if (local0 >= sn) return;   // pad chunk (sn % 16 == 0, so surviving waves are fully real)
    const u16* ap = agg + (size_t)(rowbase + (lane & 15))*128 + ((lane>>4)*8);
    bf16x8 afrag[4];
    #pragma unroll
    for (int ks = 0; ks < 4; ++ks)
        afrag[ks] = *(const bf16x8*)(ap + ks*32);
    const u16* wfp = Wf + g*16384;
    f32x4 acc[8];
    #pragma unroll
    for (int ct = 0; ct < 8; ++ct) acc[ct] = (f32x4){0.f,0.f,0.f,0.f};
    #pragma unroll
    for (int ks = 0; ks < 4; ++ks){
        #pragma unroll
        for (int ct = 0; ct < 8; ++ct){
            bf16x8 b = *(const bf16x8*)(wfp + ((size_t)((ct*4+ks)*64 + lane))*8);
            acc[ct] = __builtin_amdgcn_mfma_f32_16x16x32_bf16(afrag[ks], b, acc[ct], 0, 0, 0);
        }
    }
    int rlo = (lane>>4)*4;
    int colb = lane & 15;
    if (g == 3){
        #pragma unroll
        for (int ct = 0; ct < 8; ++ct){
            #pragma unroll
            for (int j = 0; j < 4; ++j){
                size_t idx = (size_t)(local0 + rlo + j)*128 + ct*16 + colb;
                outstu[idx] = acc[ct][j] + resid[idx];
            }
        }
    } else {
        #pragma unroll
        for (int ct = 0; ct < 8; ++ct){
            #pragma unroll
            for (int j = 0; j < 4; ++j){
                size_t idx = (size_t)(gb + local0 + rlo + j)*128 + ct*16 + colb;
                gout[idx] = f2bf(acc[ct][j]);
            }
        }
    }
}

// ------------------------------------------------- gating epilogue (kn & exer), f32 out
__global__ __launch_bounds__(256) void fuse_epi(const float* __restrict__ A,
    const u16* __restrict__ C, const u16* __restrict__ D,
    const float* __restrict__ w2, const float* __restrict__ b2,
    const float* __restrict__ w3, const float* __restrict__ b3,
    float* __restrict__ outp, int n)
{
    int w = (int)((blockIdx.x*(u32)blockDim.x + threadIdx.x) >> 6);
    int lane = threadIdx.x & 63;
    if (w >= n) return;
    int c = lane*2;
    float2 av = *(const float2*)(A + (size_t)w*128 + c);
    u32 cv = *(const u32*)(C + (size_t)w*128 + c);
    u32 dv = *(const u32*)(D + (size_t)w*128 + c);
    float c0 = bf2f((u16)cv), c1 = bf2f((u16)(cv>>16));
    float d0 = bf2f((u16)dv), d1 = bf2f((u16)(dv>>16));
    float s2 = av.x*w2[c] + av.y*w2[c+1] + c0*w2[128+c] + c1*w2[128+c+1];
    float s3 = av.x*w3[c] + av.y*w3[c+1] + d0*w3[128+c] + d1*w3[128+c+1];
    #pragma unroll
    for (int o = 32; o; o >>= 1){ s2 += __shfl_xor(s2, o); s3 += __shfl_xor(s3, o); }
    s2 += b2[0]; s3 += b3[0];
    float m = fmaxf(s2, s3);
    float e2 = __expf(s2 - m), e3 = __expf(s3 - m);
    float inv = 1.f/(e2 + e3);
    float p2 = e2*inv, p3 = e3*inv;
    float2 r;
    r.x = av.x + p2*c0 + p3*d0;
    r.y = av.y + p2*c1 + p3*d1;
    *(float2*)(outp + (size_t)w*128 + c) = r;
}

extern "C" void kernel_launch(void* const* d_in, const int* in_sizes, int n_in,
                              void* d_out, int out_size, void* d_ws, size_t ws_size,
                              hipStream_t stream)
{
    (void)in_sizes; (void)n_in; (void)out_size;
    const float* kn   = (const float*)d_in[0];
    const float* exer = (const float*)d_in[1];
    const float* stu  = (const float*)d_in[2];
    const int* und_src = (const int*)d_in[3];
    const int* und_dst = (const int*)d_in[4];
    const int* ek_src  = (const int*)d_in[5];
    const int* ek_dst  = (const int*)d_in[6];
    const int* eu_src  = (const int*)d_in[7];
    const int* eu_dst  = (const int*)d_in[8];
    const float* W_und = (const float*)d_in[9];  const float* a_und = (const float*)d_in[10];
    const float* W_ek  = (const float*)d_in[11]; const float* a_ek  = (const float*)d_in[12];
    const float* W_ke  = (const float*)d_in[13]; const float* a_ke  = (const float*)d_in[14];
    const float* W_eu  = (const float*)d_in[15]; const float* a_eu  = (const float*)d_in[16];
    const float* W_ue  = (const float*)d_in[17]; const float* a_ue  = (const float*)d_in[18];
    const float* kfc2w = (const float*)d_in[19]; const float* kfc2b = (const float*)d_in[20];
    const float* kfc3w = (const float*)d_in[21]; const float* kfc3b = (const float*)d_in[22];
    const float* efc1w = (const float*)d_in[23]; const float* efc1b = (const float*)d_in[24];
    const float* efc2w = (const float*)d_in[25]; const float* efc2b = (const float*)d_in[26];

    char* base = (char*)d_ws;
    size_t off_b = 0;
    auto alloc = [&](size_t bytes)->char*{
        char* p = base + off_b;
        off_b += (bytes + 255) & ~(size_t)255;
        return p;
    };
    float* vecs = (float*)alloc(1280*4);
    u16*   Wf   = (u16*)  alloc(5*16384*2);
    float* el1 = (float*)alloc(N_K*4);  float* er1 = (float*)alloc(N_K*4);
    float* er2 = (float*)alloc(N_K*4);  float* el3 = (float*)alloc(N_K*4);
    float* el2 = (float*)alloc(N_E*4);  float* er3 = (float*)alloc(N_E*4);
    float* el4 = (float*)alloc(N_E*4);  float* er5 = (float*)alloc(N_E*4);
    float* er4 = (float*)alloc(N_U*4);  float* el5 = (float*)alloc(N_U*4);
    int* cnt  = (int*)alloc((size_t)N_TOT*4);
    int* offA = (int*)alloc((size_t)N_TOT*4);
    int* cur  = (int*)alloc((size_t)N_TOT*4);
    int* bsum = (int*)alloc(1024*4);
    int* sorted = (int*)alloc((size_t)E_TOT*4);
    u16* agg  = (u16*)alloc((size_t)PTOT*128*2);
    u16* gout = (u16*)alloc((size_t)GTOT*128*2);
    u16* knb   = (u16*)alloc((size_t)N_K*128*2);
    u16* exerb = (u16*)alloc((size_t)N_E*128*2);
    u16* stub  = (u16*)alloc((size_t)N_U*128*2);
    size_t need_bf = off_b;
    bool useBF = (ws_size >= need_bf);      // bf16-gather path needs ~155 MB total
    float* out = (float*)d_out;

    const int NBLK = (N_TOT + 255)/256;     // 938 (<=1024 for scan2)

    hipMemsetAsync(cnt, 0, (size_t)N_TOT*4, stream);

    prep_vecs<<<10,128,0,stream>>>(W_und,W_ek,W_ke,W_eu,W_ue, a_und,a_ek,a_ke,a_eu,a_ue, vecs);
    fragify<<<5,256,0,stream>>>(W_und,W_ek,W_ke,W_eu,W_ue, Wf);

    // fused conv(f32->bf16) + el/er dots; wl_g = vecs+g*128, wr_g = vecs+(5+g)*128
    // g: 0=und 1=ek 2=ke 3=eu 4=ue
    if (useBF){
        conv_dot<4,1><<<(N_K+3)/4,256,0,stream>>>(kn,   knb,   vecs+0,    vecs+640, vecs+768,  vecs+256,  el1,er1,er2,el3, N_K);
        conv_dot<4,1><<<(N_E+3)/4,256,0,stream>>>(exer, exerb, vecs+128,  vecs+896, vecs+384,  vecs+1152, el2,er3,el4,er5, N_E);
        conv_dot<2,1><<<(N_U+3)/4,256,0,stream>>>(stu,  stub,  vecs+1024, vecs+512, nullptr, nullptr, er4, el5, nullptr, nullptr, N_U);
    } else {
        conv_dot<4,0><<<(N_K+3)/4,256,0,stream>>>(kn,   nullptr, vecs+0,    vecs+640, vecs+768,  vecs+256,  el1,er1,er2,el3, N_K);
        conv_dot<4,0><<<(N_E+3)/4,256,0,stream>>>(exer, nullptr, vecs+128,  vecs+896, vecs+384,  vecs+1152, el2,er3,el4,er5, N_E);
        conv_dot<2,0><<<(N_U+3)/4,256,0,stream>>>(stu,  nullptr, vecs+1024, vecs+512, nullptr, nullptr, er4, el5, nullptr, nullptr, N_U);
    }

    count_all<<<(E_TOT+255)/256,256,0,stream>>>(und_dst, ek_src, ek_dst, eu_src, eu_dst, cnt);
    scan1<<<NBLK,256,0,stream>>>(cnt, offA, bsum, N_TOT);
    scan2<<<1,1024,0,stream>>>(bsum, NBLK);
    scan3<<<NBLK,256,0,stream>>>(offA, cur, bsum, N_TOT);

    // range-partitioned fill: 4 sequential passes, each writing a ~2.2 MB
    // L2-resident slice of `sorted` (fixes 133 MB random-write traffic)
    {
        const int KR = (N_TOT + 3) / 4;   // 60000
        for (int p = 0; p < 4; ++p){
            fill_all<<<(E_TOT+255)/256,256,0,stream>>>(und_src, und_dst, ek_src, ek_dst,
                                                       eu_src, eu_dst, cur, sorted,
                                                       p*KR, (p == 3) ? N_TOT : (p+1)*KR);
        }
    }

    if (useBF){
        aggregate_all<1><<<(PTOT+3)/4,256,0,stream>>>(cnt, offA, sorted,
            el1,el2,el3,el4,el5, er1,er2,er3,er4,er5, knb, exerb, stub, agg);
    } else {
        aggregate_all<0><<<(PTOT+3)/4,256,0,stream>>>(cnt, offA, sorted,
            el1,el2,el3,el4,el5, er1,er2,er3,er4,er5, kn, exer, stu, agg);
    }

    gemm_all<<<PTOT/64,256,0,stream>>>(agg, Wf, gout, out + (size_t)(N_K+N_E)*128, stu);

    fuse_epi<<<(N_K+3)/4,256,0,stream>>>(kn,   gout + (size_t)PB1*128, gout + (size_t)PB2*128,
                                         kfc2w,kfc2b,kfc3w,kfc3b, out, N_K);
    fuse_epi<<<(N_E+3)/4,256,0,stream>>>(exer, gout + (size_t)PB3*128, gout + (size_t)GB5*128,
                                         efc1w,efc1b,efc2w,efc2b, out + (size_t)N_K*128, N_E);
}

// Round 6
// 432.597 us; speedup vs baseline: 1.4848x; 1.1149x over previous
//
#include <hip/hip_runtime.h>

#define N_K 20000
#define N_E 50000
#define N_U 100000
#define E_UND 200000
#define E_EK 400000
#define E_EU 600000
#define E_TOT 2200000
#define N_TOT 240000
// padded (64-aligned) agg-row segment bases: GAT1 kn | GAT2 kn | GAT3 exer | GAT4 stu | GAT5 exer
#define PB1 0
#define PB2 20032
#define PB3 40064
#define PB4 90112
#define PB5 190144
#define PTOT 240192
// key-space (concat dst) bases — also the erc concat layout
#define KB1 0
#define KB2 20000
#define KB3 40000
#define KB4 90000
#define KB5 190000

typedef unsigned short u16;
typedef unsigned int u32;
typedef __bf16 bf16x8 __attribute__((ext_vector_type(8)));
typedef float f32x4 __attribute__((ext_vector_type(4)));

__device__ __forceinline__ float bf2f(u16 v){
    union { u32 u; float f; } x; x.u = ((u32)v) << 16; return x.f;
}
__device__ __forceinline__ u16 f2bf(float f){
    union { float f; u32 u; } x; x.f = f;
    u32 r = x.u + 0x7FFFu + ((x.u >> 16) & 1u);
    return (u16)(r >> 16);
}
__device__ __forceinline__ float leaky_exp(float x){
    x = x >= 0.f ? x : 0.01f*x;
    return __expf(x);
}

// ---------------------------------------------------------------- prep: wl/wr
// wl_g = W_g @ a_g[:128] at vecs+g*128 ; wr_g = W_g @ a_g[128:] at vecs+(5+g)*128
__global__ void prep_vecs(const float* W0, const float* W1, const float* W2, const float* W3, const float* W4,
                          const float* a0, const float* a1, const float* a2, const float* a3, const float* a4,
                          float* __restrict__ vecs)
{
    int b = blockIdx.x;          // 0..9
    int g = b % 5, which = b / 5;
    const float* W = g==0?W0:g==1?W1:g==2?W2:g==3?W3:W4;
    const float* a = g==0?a0:g==1?a1:g==2?a2:g==3?a3:a4;
    const float* av = a + which*128;
    int k = threadIdx.x;         // 0..127
    float sum = 0.f;
    for (int c = 0; c < 128; ++c)
        sum += W[k*128 + c] * av[c];
    vecs[(which*5 + g)*128 + k] = sum;
}

// -------------------------------------------- W -> MFMA-B-fragment order (bf16)
// B frag of mfma_f32_16x16x32_bf16: lane l holds B[k][n], n=ct*16+(l&15),
// k = ks*32 + (l>>4)*8 + j. Linear frag index t = ct*4+ks.
__global__ void fragify(const float* W0, const float* W1, const float* W2, const float* W3, const float* W4,
                        u16* __restrict__ Wf)
{
    int g = blockIdx.x;
    const float* W = g==0?W0:g==1?W1:g==2?W2:g==3?W3:W4;
    u16* out = Wf + g*16384;
    for (int i = threadIdx.x; i < 2048; i += blockDim.x){
        int lane = i & 63, t = i >> 6, ks = t & 3, ct = t >> 2;
        int kbase = ks*32 + (lane>>4)*8;
        int c = ct*16 + (lane&15);
        #pragma unroll
        for (int j = 0; j < 8; ++j)
            out[i*8 + j] = f2bf(W[(kbase+j)*128 + c]);
    }
}

// ------------------------------------------------- fused conv(f32->bf16) + row dots
template<int ND, int WBF>
__global__ __launch_bounds__(256) void conv_dot(const float* __restrict__ h, u16* __restrict__ hb,
    const float* __restrict__ v0, const float* __restrict__ v1,
    const float* __restrict__ v2, const float* __restrict__ v3,
    float* __restrict__ o0, float* __restrict__ o1,
    float* __restrict__ o2, float* __restrict__ o3, int nrows)
{
    int w = (int)((blockIdx.x*(u32)blockDim.x + threadIdx.x) >> 6);
    int lane = threadIdx.x & 63;
    if (w >= nrows) return;
    float2 hv = *(const float2*)(h + (size_t)w*128 + lane*2);
    if (WBF)
        *(u32*)(hb + (size_t)w*128 + lane*2) = (u32)f2bf(hv.x) | ((u32)f2bf(hv.y) << 16);
    int c = lane*2;
    float d0 = hv.x*v0[c] + hv.y*v0[c+1];
    float d1 = hv.x*v1[c] + hv.y*v1[c+1];
    float d2 = 0.f, d3 = 0.f;
    if (ND == 4){
        d2 = hv.x*v2[c] + hv.y*v2[c+1];
        d3 = hv.x*v3[c] + hv.y*v3[c+1];
    }
    #pragma unroll
    for (int o = 32; o; o >>= 1){
        d0 += __shfl_xor(d0, o); d1 += __shfl_xor(d1, o);
        if (ND == 4){ d2 += __shfl_xor(d2, o); d3 += __shfl_xor(d3, o); }
    }
    if (lane == 0){
        o0[w] = d0; o1[w] = d1;
        if (ND == 4){ o2[w] = d2; o3[w] = d3; }
    }
}

// ------------------------------------------------- CSR build (all 5 graphs fused)
__global__ void count_all(const int* __restrict__ ud,
                          const int* __restrict__ es, const int* __restrict__ ed,
                          const int* __restrict__ vs, const int* __restrict__ vd,
                          int* __restrict__ cnt)
{
    int e = blockIdx.x*256 + threadIdx.x;
    if (e >= E_TOT) return;
    int dstv, nb;
    if (e < 200000){ dstv = ud[e]; nb = KB1; }
    else if (e < 600000){ dstv = ed[e-200000]; nb = KB2; }
    else if (e < 1000000){ dstv = es[e-600000]; nb = KB3; }
    else if (e < 1600000){ dstv = vd[e-1000000]; nb = KB4; }
    else { dstv = vs[e-1600000]; nb = KB5; }
    atomicAdd(&cnt[nb + dstv], 1);
}

// range-partitioned fill+edge-weight: pass handles keys in [klo,khi) only, so
// the write slice of sorted2 is L2/LLC-hot. Computes ev = exp(leaky(el+er))
// here (lane-parallel) so aggregate's per-row loop needn't (r5: VALU-bound).
__global__ void fill_ev(const int* __restrict__ us, const int* __restrict__ ud,
                        const int* __restrict__ es, const int* __restrict__ ed,
                        const int* __restrict__ vs, const int* __restrict__ vd,
                        const float* __restrict__ el1, const float* __restrict__ el2,
                        const float* __restrict__ el3, const float* __restrict__ el4,
                        const float* __restrict__ el5, const float* __restrict__ erc,
                        int* __restrict__ cur, int2* __restrict__ sorted2,
                        int klo, int khi)
{
    int e = blockIdx.x*256 + threadIdx.x;
    if (e >= E_TOT) return;
    int dstv, nb;
    if (e < 200000){ dstv = ud[e]; nb = KB1; }
    else if (e < 600000){ dstv = ed[e-200000]; nb = KB2; }
    else if (e < 1000000){ dstv = es[e-600000]; nb = KB3; }
    else if (e < 1600000){ dstv = vd[e-1000000]; nb = KB4; }
    else { dstv = vs[e-1600000]; nb = KB5; }
    int key = nb + dstv;
    if (key < klo || key >= khi) return;
    int srcv; const float* el;
    if (e < 200000){ srcv = us[e]; el = el1; }
    else if (e < 600000){ srcv = es[e-200000]; el = el2; }
    else if (e < 1000000){ srcv = ed[e-600000]; el = el3; }
    else if (e < 1600000){ srcv = vs[e-1000000]; el = el4; }
    else { srcv = vd[e-1600000]; el = el5; }
    float ev = leaky_exp(el[srcv] + erc[key]);
    int pos = atomicAdd(&cur[key], 1);
    sorted2[pos] = make_int2(srcv, __float_as_int(ev));
}

// block-level exclusive scan (Hillis-Steele in LDS)
__global__ void scan1(const int* __restrict__ cnt, int* __restrict__ off, int* __restrict__ bsum, int n){
    __shared__ int sm[256];
    int t = threadIdx.x;
    int i = blockIdx.x*256 + t;
    int v = (i < n) ? cnt[i] : 0;
    sm[t] = v; __syncthreads();
    #pragma unroll
    for (int d = 1; d < 256; d <<= 1){
        int x = (t >= d) ? sm[t-d] : 0;
        __syncthreads();
        sm[t] += x;
        __syncthreads();
    }
    if (i < n) off[i] = sm[t] - v;
    if (t == 255) bsum[blockIdx.x] = sm[255];
}

__global__ void scan2(int* __restrict__ bsum, int nb){
    __shared__ int sm[1024];
    int t = threadIdx.x;
    int v = (t < nb) ? bsum[t] : 0;
    sm[t] = v; __syncthreads();
    #pragma unroll
    for (int d = 1; d < 1024; d <<= 1){
        int x = (t >= d) ? sm[t-d] : 0;
        __syncthreads();
        sm[t] += x;
        __syncthreads();
    }
    if (t < nb) bsum[t] = sm[t] - v;
}

__global__ void scan3(int* __restrict__ off, int* __restrict__ cur, const int* __restrict__ bsum, int n){
    int i = blockIdx.x*256 + threadIdx.x;
    if (i < n){
        int v = off[i] + bsum[blockIdx.x];
        off[i] = v;
        cur[i] = v;
    }
}

// ------------------------------------------------- fused GAT aggregation (wave per dst node)
// agg[d] = (sum_e ev*h[src_e]) / (sum_e ev); ev precomputed in fill_ev.
// Inner loop: 8B broadcast load (src,ev) + one bf16x2 gather + 2 fma.
template<int BF>
__global__ __launch_bounds__(256) void aggregate_all(
    const int* __restrict__ cnt, const int* __restrict__ off, const int2* __restrict__ sorted2,
    const void* __restrict__ hk, const void* __restrict__ he, const void* __restrict__ hs,
    u16* __restrict__ agg)
{
    int row = (int)((blockIdx.x*(u32)blockDim.x + threadIdx.x) >> 6);
    int lane = threadIdx.x & 63;
    if (row >= PTOT) return;
    int local, nb, sn;
    const void* h;
    if (row < PB2){ local=row;      nb=KB1; sn=N_K; h=hk; }
    else if (row < PB3){ local=row-PB2; nb=KB2; sn=N_K; h=he; }
    else if (row < PB4){ local=row-PB3; nb=KB3; sn=N_E; h=hk; }
    else if (row < PB5){ local=row-PB4; nb=KB4; sn=N_U; h=he; }
    else {              local=row-PB5; nb=KB5; sn=N_E; h=hs; }
    if (local >= sn) return;   // 64-pad tail
    int ci = nb + local;
    int deg = cnt[ci], start = off[ci];
    float a0 = 0.f, a1 = 0.f, ssum = 0.f;
    const u32* hb32 = (const u32*)h;
    const float2* hf2 = (const float2*)h;
    int i = 0;
    for (; i + 8 <= deg; i += 8){
        int2 w[8];
        #pragma unroll
        for (int j = 0; j < 8; ++j) w[j] = sorted2[start+i+j];
        if (BF){
            u32 hv[8];
            #pragma unroll
            for (int j = 0; j < 8; ++j) hv[j] = hb32[(size_t)w[j].x*64 + lane];
            #pragma unroll
            for (int j = 0; j < 8; ++j){
                float ev = __int_as_float(w[j].y);
                a0 = fmaf(ev, bf2f((u16)hv[j]), a0);
                a1 = fmaf(ev, bf2f((u16)(hv[j]>>16)), a1);
                ssum += ev;
            }
        } else {
            float2 hv[8];
            #pragma unroll
            for (int j = 0; j < 8; ++j) hv[j] = hf2[(size_t)w[j].x*64 + lane];
            #pragma unroll
            for (int j = 0; j < 8; ++j){
                float ev = __int_as_float(w[j].y);
                a0 = fmaf(ev, hv[j].x, a0);
                a1 = fmaf(ev, hv[j].y, a1);
                ssum += ev;
            }
        }
    }
    for (; i + 4 <= deg; i += 4){
        int2 w[4];
        #pragma unroll
        for (int j = 0; j < 4; ++j) w[j] = sorted2[start+i+j];
        if (BF){
            u32 hv[4];
            #pragma unroll
            for (int j = 0; j < 4; ++j) hv[j] = hb32[(size_t)w[j].x*64 + lane];
            #pragma unroll
            for (int j = 0; j < 4; ++j){
                float ev = __int_as_float(w[j].y);
                a0 = fmaf(ev, bf2f((u16)hv[j]), a0);
                a1 = fmaf(ev, bf2f((u16)(hv[j]>>16)), a1);
                ssum += ev;
            }
        } else {
            float2 hv[4];
            #pragma unroll
            for (int j = 0; j < 4; ++j) hv[j] = hf2[(size_t)w[j].x*64 + lane];
            #pragma unroll
            for (int j = 0; j < 4; ++j){
                float ev = __int_as_float(w[j].y);
                a0 = fmaf(ev, hv[j].x, a0);
                a1 = fmaf(ev, hv[j].y, a1);
                ssum += ev;
            }
        }
    }
    for (; i < deg; ++i){
        int2 w = sorted2[start + i];
        float ev = __int_as_float(w.y);
        float x0, x1;
        if (BF){
            u32 hv = hb32[(size_t)w.x*64 + lane];
            x0 = bf2f((u16)hv); x1 = bf2f((u16)(hv>>16));
        } else {
            float2 hv = hf2[(size_t)w.x*64 + lane];
            x0 = hv.x; x1 = hv.y;
        }
        a0 = fmaf(ev, x0, a0);
        a1 = fmaf(ev, x1, a1);
        ssum += ev;
    }
    float inv = (ssum > 0.f) ? 1.f/ssum : 0.f;   // deg==0 -> zero row (matches reference)
    *(u32*)(agg + (size_t)row*128 + lane*2) = (u32)f2bf(a0*inv) | ((u32)f2bf(a1*inv) << 16);
}

// ------------------------------------------------- fused dual-GEMM + gating epilogue
// kn blocks:   C = agg[PB1+r]@W0, D = agg[PB2+r]@W1, gate(kfc2,kfc3), out rows [0,N_K)
// exer blocks: C = agg[PB3+r]@W2, D = agg[PB5+r]@W4, gate(efc1,efc2), out rows [N_K,N_K+N_E)
// stu blocks:  single GEMM agg[PB4+r]@W3 + resid -> out rows [N_K+N_E, ...)
// All sn are multiples of 16 -> per-wave all-or-nothing tail handling.
#define KBLK 313
#define EBLK 782
#define SBLK 1563
__global__ __launch_bounds__(256) void gemm_epi(const u16* __restrict__ agg, const u16* __restrict__ Wf,
    const float* __restrict__ kn, const float* __restrict__ exer, const float* __restrict__ stu,
    const float* __restrict__ kfc2w, const float* __restrict__ kfc2b,
    const float* __restrict__ kfc3w, const float* __restrict__ kfc3b,
    const float* __restrict__ efc1w, const float* __restrict__ efc1b,
    const float* __restrict__ efc2w, const float* __restrict__ efc2b,
    float* __restrict__ out)
{
    int wave = threadIdx.x >> 6, lane = threadIdx.x & 63;
    int bid = blockIdx.x;
    int kind, r0, sn, baseC, baseD;
    const u16 *wc, *wd;
    const float *A, *w2, *b2, *w3, *b3;
    float* outp;
    if (bid < KBLK){
        kind=0; r0=bid*64; sn=N_K; baseC=PB1; baseD=PB2;
        wc=Wf; wd=Wf+16384; A=kn; w2=kfc2w; b2=kfc2b; w3=kfc3w; b3=kfc3b; outp=out;
    } else if (bid < KBLK+EBLK){
        kind=0; r0=(bid-KBLK)*64; sn=N_E; baseC=PB3; baseD=PB5;
        wc=Wf+2*16384; wd=Wf+4*16384; A=exer; w2=efc1w; b2=efc1b; w3=efc2w; b3=efc2b;
        outp=out + (size_t)N_K*128;
    } else {
        kind=1; r0=(bid-KBLK-EBLK)*64; sn=N_U; baseC=PB4; baseD=PB4;
        wc=Wf+3*16384; wd=nullptr; A=stu; w2=nullptr; b2=nullptr; w3=nullptr; b3=nullptr;
        outp=out + (size_t)(N_K+N_E)*128;
    }
    int lrow = r0 + wave*16;
    if (lrow >= sn) return;           // sn % 16 == 0 -> whole-wave validity
    int colb = lane & 15;
    int rlo  = (lane>>4)*4;

    // --- C gemm ---
    f32x4 accC[8];
    #pragma unroll
    for (int ct = 0; ct < 8; ++ct) accC[ct] = (f32x4){0.f,0.f,0.f,0.f};
    {
        const u16* ap = agg + (size_t)(baseC + lrow + colb)*128 + ((lane>>4)*8);
        bf16x8 af[4];
        #pragma unroll
        for (int ks = 0; ks < 4; ++ks) af[ks] = *(const bf16x8*)(ap + ks*32);
        #pragma unroll
        for (int ks = 0; ks < 4; ++ks)
            #pragma unroll
            for (int ct = 0; ct < 8; ++ct){
                bf16x8 b = *(const bf16x8*)(wc + ((size_t)((ct*4+ks)*64 + lane))*8);
                accC[ct] = __builtin_amdgcn_mfma_f32_16x16x32_bf16(af[ks], b, accC[ct], 0, 0, 0);
            }
    }

    if (kind == 1){
        // student: out = acc + resid
        #pragma unroll
        for (int ct = 0; ct < 8; ++ct)
            #pragma unroll
            for (int j = 0; j < 4; ++j){
                size_t idx = (size_t)(lrow + rlo + j)*128 + ct*16 + colb;
                outp[idx] = accC[ct][j] + A[idx];
            }
        return;
    }

    // --- D gemm ---
    f32x4 accD[8];
    #pragma unroll
    for (int ct = 0; ct < 8; ++ct) accD[ct] = (f32x4){0.f,0.f,0.f,0.f};
    {
        const u16* ap = agg + (size_t)(baseD + lrow + colb)*128 + ((lane>>4)*8);
        bf16x8 af[4];
        #pragma unroll
        for (int ks = 0; ks < 4; ++ks) af[ks] = *(const bf16x8*)(ap + ks*32);
        #pragma unroll
        for (int ks = 0; ks < 4; ++ks)
            #pragma unroll
            for (int ct = 0; ct < 8; ++ct){
                bf16x8 b = *(const bf16x8*)(wd + ((size_t)((ct*4+ks)*64 + lane))*8);
                accD[ct] = __builtin_amdgcn_mfma_f32_16x16x32_bf16(af[ks], b, accD[ct], 0, 0, 0);
            }
    }

    // --- gating epilogue ---
    float w2l[8], w2h[8], w3l[8], w3h[8];
    #pragma unroll
    for (int ct = 0; ct < 8; ++ct){
        int c = ct*16 + colb;
        w2l[ct] = w2[c]; w2h[ct] = w2[128+c];
        w3l[ct] = w3[c]; w3h[ct] = w3[128+c];
    }
    float aA[8][4];
    #pragma unroll
    for (int ct = 0; ct < 8; ++ct)
        #pragma unroll
        for (int j = 0; j < 4; ++j)
            aA[ct][j] = A[(size_t)(lrow + rlo + j)*128 + ct*16 + colb];
    float s2p[4] = {0.f,0.f,0.f,0.f}, s3p[4] = {0.f,0.f,0.f,0.f};
    #pragma unroll
    for (int ct = 0; ct < 8; ++ct)
        #pragma unroll
        for (int j = 0; j < 4; ++j){
            s2p[j] = fmaf(aA[ct][j], w2l[ct], fmaf(accC[ct][j], w2h[ct], s2p[j]));
            s3p[j] = fmaf(aA[ct][j], w3l[ct], fmaf(accD[ct][j], w3h[ct], s3p[j]));
        }
    #pragma unroll
    for (int m = 8; m; m >>= 1)
        #pragma unroll
        for (int j = 0; j < 4; ++j){
            s2p[j] += __shfl_xor(s2p[j], m);
            s3p[j] += __shfl_xor(s3p[j], m);
        }
    float bb2 = b2[0], bb3 = b3[0];
    #pragma unroll
    for (int j = 0; j < 4; ++j){
        float s2 = s2p[j] + bb2, s3 = s3p[j] + bb3;
        float mx = fmaxf(s2, s3);
        float e2 = __expf(s2 - mx), e3 = __expf(s3 - mx);
        float inv = 1.f/(e2 + e3);
        float p2 = e2*inv, p3 = e3*inv;
        #pragma unroll
        for (int ct = 0; ct < 8; ++ct){
            size_t idx = (size_t)(lrow + rlo + j)*128 + ct*16 + colb;
            outp[idx] = aA[ct][j] + p2*accC[ct][j] + p3*accD[ct][j];
        }
    }
}

extern "C" void kernel_launch(void* const* d_in, const int* in_sizes, int n_in,
                              void* d_out, int out_size, void* d_ws, size_t ws_size,
                              hipStream_t stream)
{
    (void)in_sizes; (void)n_in; (void)out_size;
    const float* kn   = (const float*)d_in[0];
    const float* exer = (const float*)d_in[1];
    const float* stu  = (const float*)d_in[2];
    const int* und_src = (const int*)d_in[3];
    const int* und_dst = (const int*)d_in[4];
    const int* ek_src  = (const int*)d_in[5];
    const int* ek_dst  = (const int*)d_in[6];
    const int* eu_src  = (const int*)d_in[7];
    const int* eu_dst  = (const int*)d_in[8];
    const float* W_und = (const float*)d_in[9];  const float* a_und = (const float*)d_in[10];
    const float* W_ek  = (const float*)d_in[11]; const float* a_ek  = (const float*)d_in[12];
    const float* W_ke  = (const float*)d_in[13]; const float* a_ke  = (const float*)d_in[14];
    const float* W_eu  = (const float*)d_in[15]; const float* a_eu  = (const float*)d_in[16];
    const float* W_ue  = (const float*)d_in[17]; const float* a_ue  = (const float*)d_in[18];
    const float* kfc2w = (const float*)d_in[19]; const float* kfc2b = (const float*)d_in[20];
    const float* kfc3w = (const float*)d_in[21]; const float* kfc3b = (const float*)d_in[22];
    const float* efc1w = (const float*)d_in[23]; const float* efc1b = (const float*)d_in[24];
    const float* efc2w = (const float*)d_in[25]; const float* efc2b = (const float*)d_in[26];

    char* base = (char*)d_ws;
    size_t off_b = 0;
    auto alloc = [&](size_t bytes)->char*{
        char* p = base + off_b;
        off_b += (bytes + 255) & ~(size_t)255;
        return p;
    };
    float* vecs = (float*)alloc(1280*4);
    u16*   Wf   = (u16*)  alloc(5*16384*2);
    float* el1 = (float*)alloc(N_K*4);
    float* el2 = (float*)alloc(N_E*4);
    float* el3 = (float*)alloc(N_K*4);
    float* el4 = (float*)alloc(N_E*4);
    float* el5 = (float*)alloc(N_U*4);
    float* erc = (float*)alloc((size_t)N_TOT*4);     // concat er, indexed by key
    int* cnt  = (int*)alloc((size_t)N_TOT*4);
    int* offA = (int*)alloc((size_t)N_TOT*4);
    int* cur  = (int*)alloc((size_t)N_TOT*4);
    int* bsum = (int*)alloc(1024*4);
    int2* sorted2 = (int2*)alloc((size_t)E_TOT*8);   // {src, ev}
    u16* agg  = (u16*)alloc((size_t)PTOT*128*2);
    u16* knb   = (u16*)alloc((size_t)N_K*128*2);
    u16* exerb = (u16*)alloc((size_t)N_E*128*2);
    u16* stub  = (u16*)alloc((size_t)N_U*128*2);
    size_t need_bf = off_b;
    bool useBF = (ws_size >= need_bf);
    float* out = (float*)d_out;

    const int NBLK = (N_TOT + 255)/256;     // 938 (<=1024 for scan2)

    hipMemsetAsync(cnt, 0, (size_t)N_TOT*4, stream);

    prep_vecs<<<10,128,0,stream>>>(W_und,W_ek,W_ke,W_eu,W_ue, a_und,a_ek,a_ke,a_eu,a_ue, vecs);
    fragify<<<5,256,0,stream>>>(W_und,W_ek,W_ke,W_eu,W_ue, Wf);

    // fused conv(f32->bf16) + el/er dots; wl_g = vecs+g*128, wr_g = vecs+(5+g)*128
    // g: 0=und 1=ek 2=ke 3=eu 4=ue.  er outputs go straight into erc at key bases.
    if (useBF){
        conv_dot<4,1><<<(N_K+3)/4,256,0,stream>>>(kn,   knb,   vecs+0,    vecs+640, vecs+768,  vecs+256,  el1, erc+KB1, erc+KB2, el3, N_K);
        conv_dot<4,1><<<(N_E+3)/4,256,0,stream>>>(exer, exerb, vecs+128,  vecs+896, vecs+384,  vecs+1152, el2, erc+KB3, el4, erc+KB5, N_E);
        conv_dot<2,1><<<(N_U+3)/4,256,0,stream>>>(stu,  stub,  vecs+1024, vecs+512, nullptr, nullptr, erc+KB4, el5, nullptr, nullptr, N_U);
    } else {
        conv_dot<4,0><<<(N_K+3)/4,256,0,stream>>>(kn,   nullptr, vecs+0,    vecs+640, vecs+768,  vecs+256,  el1, erc+KB1, erc+KB2, el3, N_K);
        conv_dot<4,0><<<(N_E+3)/4,256,0,stream>>>(exer, nullptr, vecs+128,  vecs+896, vecs+384,  vecs+1152, el2, erc+KB3, el4, erc+KB5, N_E);
        conv_dot<2,0><<<(N_U+3)/4,256,0,stream>>>(stu,  nullptr, vecs+1024, vecs+512, nullptr, nullptr, erc+KB4, el5, nullptr, nullptr, N_U);
    }

    count_all<<<(E_TOT+255)/256,256,0,stream>>>(und_dst, ek_src, ek_dst, eu_src, eu_dst, cnt);
    scan1<<<NBLK,256,0,stream>>>(cnt, offA, bsum, N_TOT);
    scan2<<<1,1024,0,stream>>>(bsum, NBLK);
    scan3<<<NBLK,256,0,stream>>>(offA, cur, bsum, N_TOT);

    // range-partitioned fill (4 passes): L2/LLC-hot write slices + ev precompute
    {
        const int KR = (N_TOT + 3) / 4;   // 60000
        for (int p = 0; p < 4; ++p){
            fill_ev<<<(E_TOT+255)/256,256,0,stream>>>(und_src, und_dst, ek_src, ek_dst,
                                                      eu_src, eu_dst,
                                                      el1, el2, el3, el4, el5, erc,
                                                      cur, sorted2,
                                                      p*KR, (p == 3) ? N_TOT : (p+1)*KR);
        }
    }

    if (useBF){
        aggregate_all<1><<<(PTOT+3)/4,256,0,stream>>>(cnt, offA, sorted2, knb, exerb, stub, agg);
    } else {
        aggregate_all<0><<<(PTOT+3)/4,256,0,stream>>>(cnt, offA, sorted2, kn, exer, stu, agg);
    }

    gemm_epi<<<KBLK+EBLK+SBLK,256,0,stream>>>(agg, Wf, kn, exer, stu,
                                              kfc2w,kfc2b,kfc3w,kfc3b,
                                              efc1w,efc1b,efc2w,efc2b, out);
}